// Round 4
// baseline (92.094 us; speedup 1.0000x reference)
//
#include <hip/hip_runtime.h>
#include <hip/hip_bf16.h>

#define C_DIM 320
#define N_DIM 4096
#define NEG 0.01f

typedef float f32x4 __attribute__((ext_vector_type(4)));
typedef short bf16x8 __attribute__((ext_vector_type(8)));
typedef __bf16 bfv8 __attribute__((ext_vector_type(8)));

__device__ __forceinline__ float lrelu(float e) { return fmaxf(e, NEG * e); }

__device__ __forceinline__ void gload_lds16(const void* g, void* l) {
    __builtin_amdgcn_global_load_lds(
        (const __attribute__((address_space(1))) void*)g,
        (__attribute__((address_space(3))) void*)l, 16, 0, 0);
}

// ===================== fast path =====================

// partial dot products (c-split 5) + bf16 conversion of x
__global__ __launch_bounds__(256) void k_s12(const float* __restrict__ x,
                                             const float* __restrict__ W,
                                             float* __restrict__ s1p,
                                             float* __restrict__ s2p,
                                             short* __restrict__ xb) {
    const int b = blockIdx.z, cb = blockIdx.y;
    const int nl = threadIdx.x & 63, cw = threadIdx.x >> 6;
    const int n = blockIdx.x * 64 + nl;
    const int cbase = cb * 64 + cw * 16;
    const float* px = x + ((size_t)b * C_DIM + cbase) * N_DIM + n;
    short* pxb = xb + ((size_t)b * C_DIM + cbase) * N_DIM + n;
    const float* w1 = W + cbase;
    const float* w2 = W + C_DIM + cbase;
    float a1 = 0.f, a2 = 0.f;
    #pragma unroll
    for (int cc = 0; cc < 16; ++cc) {
        float v = px[(size_t)cc * N_DIM];
        a1 = fmaf(v, w1[cc], a1);
        a2 = fmaf(v, w2[cc], a2);
        __hip_bfloat16 hv = __float2bfloat16(v);
        pxb[(size_t)cc * N_DIM] = *(short*)&hv;
    }
    __shared__ float r1[4][64], r2[4][64];
    r1[cw][nl] = a1; r2[cw][nl] = a2;
    __syncthreads();
    if (threadIdx.x < 64) {
        float t1 = r1[0][nl] + r1[1][nl] + r1[2][nl] + r1[3][nl];
        float t2 = r2[0][nl] + r2[1][nl] + r2[2][nl] + r2[3][nl];
        s1p[((size_t)b * 5 + cb) * N_DIM + n] = t1;
        s2p[((size_t)b * 5 + cb) * N_DIM + n] = t2;
    }
}

// fold partials -> s2, Ek, Gk, s1max
__global__ __launch_bounds__(1024) void k_fold(const float* __restrict__ s1p,
                                               const float* __restrict__ s2p,
                                               float* __restrict__ s2,
                                               float* __restrict__ Ekf,
                                               float* __restrict__ Gkf,
                                               float* __restrict__ s1max) {
    const int b = blockIdx.x, tid = threadIdx.x;
    __shared__ float md[1024];
    float mx = -3.4e38f;
    for (int n = tid; n < N_DIM; n += 1024) {
        float v1 = 0.f, v2 = 0.f;
        #pragma unroll
        for (int cb = 0; cb < 5; ++cb) {
            v1 += s1p[((size_t)b * 5 + cb) * N_DIM + n];
            v2 += s2p[((size_t)b * 5 + cb) * N_DIM + n];
        }
        s2[b * N_DIM + n] = v2;
        Ekf[b * N_DIM + n] = __expf(v1);
        Gkf[b * N_DIM + n] = __expf(NEG * v1);
        mx = fmaxf(mx, v1);
    }
    md[tid] = mx;
    __syncthreads();
    for (int s = 512; s > 0; s >>= 1) {
        if (tid < s) md[tid] = fmaxf(md[tid], md[tid + s]);
        __syncthreads();
    }
    if (tid == 0) s1max[b] = md[0];
}

// per row: Z = sum_k max(Ek*F, Gk*H); store Fz=F/Z, Hz=H/Z. E/G staged in LDS.
__global__ __launch_bounds__(256) void k_z(const float* __restrict__ s2,
                                           const float* __restrict__ s1max,
                                           const float* __restrict__ Ekf,
                                           const float* __restrict__ Gkf,
                                           float* __restrict__ Fz,
                                           float* __restrict__ Hz) {
    __shared__ __align__(16) float Els[4096], Gls[4096];
    const int b = blockIdx.y, tid = threadIdx.x;
    const int w = tid >> 6, l = tid & 63;
    const float* Eb = Ekf + b * N_DIM;
    const float* Gb = Gkf + b * N_DIM;
    #pragma unroll
    for (int i = 0; i < 4; ++i) {
        int ch = i * 256 + tid;
        *(f32x4*)&Els[ch * 4] = *(const f32x4*)&Eb[ch * 4];
        *(f32x4*)&Gls[ch * 4] = *(const f32x4*)&Gb[ch * 4];
    }
    __syncthreads();
    float smax = s1max[b];
    #pragma unroll
    for (int rr = 0; rr < 4; ++rr) {
        int row = b * N_DIM + blockIdx.x * 16 + w * 4 + rr;
        float s2n = s2[row];
        float mn = lrelu(s2n + smax);
        float F = __expf(s2n - mn), H = __expf(NEG * s2n - mn);
        float sum = 0.f;
        #pragma unroll 4
        for (int i = 0; i < 16; ++i) {
            int k = i * 256 + l * 4;
            f32x4 e = *(const f32x4*)&Els[k];
            f32x4 gg = *(const f32x4*)&Gls[k];
            #pragma unroll
            for (int j = 0; j < 4; ++j) sum += fmaxf(e[j] * F, gg[j] * H);
        }
        #pragma unroll
        for (int off = 32; off > 0; off >>= 1) sum += __shfl_down(sum, off);
        if (l == 0) {
            float rz = 1.f / sum;
            Fz[row] = F * rz;
            Hz[row] = H * rz;
        }
    }
}

// fused GEMM: out[b,c,n] = sum_k P[c,k]*Q[k,n] + P[c,n]
// Q[k,n] = max(Ek[k]*Fz[n], Gk[k]*Hz[n]) bf16, generated in registers.
// grid (128 n, 5 c, 2 b), 256 thr = 4 waves, K-split 4 (each wave K=1024).
// Wave tile 64c x 32n. Per-wave private LDS dbuf (4KB x2), barrier-free K-loop,
// counted vmcnt(4); E/G loaded to regs via inline-asm global_load_dwordx4.
__global__ __launch_bounds__(256) void k_gemm(const short* __restrict__ xb,
                                              const float* __restrict__ x,
                                              const float* __restrict__ Ekf,
                                              const float* __restrict__ Gkf,
                                              const float* __restrict__ Fz,
                                              const float* __restrict__ Hz,
                                              float* __restrict__ out) {
    __shared__ __align__(16) short Asm[4][2][2048];   // 32 KB

    const int b = blockIdx.z, c0 = blockIdx.y * 64, n0 = blockIdx.x * 32;
    const int tid = threadIdx.x;
    const int h = tid >> 6, l = tid & 63, lr = l & 15, g = (l >> 4) & 3;
    const int kbase = h * 1024;

    const short* xbp = xb + (size_t)b * C_DIM * N_DIM;
    const float* Eb = Ekf + b * N_DIM + kbase;
    const float* Gb = Gkf + b * N_DIM + kbase;

    // B-column constants
    int ncol[2]; float fz[2], hz[2];
    #pragma unroll
    for (int t = 0; t < 2; ++t) {
        int n = n0 + t * 16 + lr;
        ncol[t] = n;
        fz[t] = Fz[b * N_DIM + n];
        hz[t] = Hz[b * N_DIM + n];
    }

    // per-lane pre-swizzled stage source pointers (superrow layout:
    // slot sidx = q*64+l -> r=sidx>>3, j=sidx&7; logical jl=j^(r&7);
    // row=2r+(jl>>2), k-granule=jl&3)
    const short* sp0; const short* sp1; const short* sp2; const short* sp3;
    {
        #pragma unroll
        for (int q = 0; q < 4; ++q) {
            int sidx = q * 64 + l;
            int r = sidx >> 3, j = sidx & 7;
            int jl = j ^ (r & 7);
            int row = 2 * r + (jl >> 2);
            int gk = jl & 3;
            const short* p = xbp + (size_t)(c0 + row) * N_DIM + kbase + gk * 8;
            if (q == 0) sp0 = p; else if (q == 1) sp1 = p;
            else if (q == 2) sp2 = p; else sp3 = p;
        }
    }
    // read offset (shorts) within a buf for frag i: i*512 + roff
    const int roff = (lr >> 1) * 64 + (((((lr & 1) << 2) | g) ^ (lr >> 1)) * 8);

    f32x4 acc[4][2];
    #pragma unroll
    for (int i = 0; i < 4; ++i)
        #pragma unroll
        for (int t = 0; t < 2; ++t) acc[i][t] = (f32x4){0.f, 0.f, 0.f, 0.f};

    f32x4 E0, E1, G0, G1;

    #define STAGE(buf, it)                                            \
        do {                                                          \
            gload_lds16(sp0 + (it) * 32, &Asm[h][buf][0]);            \
            gload_lds16(sp1 + (it) * 32, &Asm[h][buf][512]);          \
            gload_lds16(sp2 + (it) * 32, &Asm[h][buf][1024]);         \
            gload_lds16(sp3 + (it) * 32, &Asm[h][buf][1536]);         \
        } while (0)

    #define LOADEG(it)                                                              \
        do {                                                                        \
            const float* pe = Eb + (it) * 32 + g * 8;                               \
            const float* pg = Gb + (it) * 32 + g * 8;                               \
            asm volatile("global_load_dwordx4 %0, %1, off"                          \
                         : "=&v"(E0) : "v"(pe) : "memory");                         \
            asm volatile("global_load_dwordx4 %0, %1, off offset:16"                \
                         : "=&v"(E1) : "v"(pe) : "memory");                         \
            asm volatile("global_load_dwordx4 %0, %1, off"                          \
                         : "=&v"(G0) : "v"(pg) : "memory");                         \
            asm volatile("global_load_dwordx4 %0, %1, off offset:16"                \
                         : "=&v"(G1) : "v"(pg) : "memory");                         \
        } while (0)

    #define GENB(bfr, t)                                                        \
        do {                                                                    \
            bfv8 qv;                                                            \
            _Pragma("unroll")                                                   \
            for (int j = 0; j < 4; ++j) {                                       \
                qv[j]     = (__bf16)fmaxf(E0[j] * fz[t], G0[j] * hz[t]);        \
                qv[j + 4] = (__bf16)fmaxf(E1[j] * fz[t], G1[j] * hz[t]);        \
            }                                                                   \
            bfr = __builtin_bit_cast(bf16x8, qv);                               \
        } while (0)

    #define COMPUTE(buf, bfr0, bfr1)                                            \
        do {                                                                    \
            const short* Ab = &Asm[h][buf][0];                                  \
            _Pragma("unroll")                                                   \
            for (int i = 0; i < 4; ++i) {                                       \
                bf16x8 afr = *(const bf16x8*)(Ab + i * 512 + roff);             \
                acc[i][0] = __builtin_amdgcn_mfma_f32_16x16x32_bf16(            \
                    afr, bfr0, acc[i][0], 0, 0, 0);                             \
                acc[i][1] = __builtin_amdgcn_mfma_f32_16x16x32_bf16(            \
                    afr, bfr1, acc[i][1], 0, 0, 0);                             \
            }                                                                   \
        } while (0)

    STAGE(0, 0);
    LOADEG(0);
    for (int it = 0; it < 31; ++it) {
        const int buf = it & 1;
        STAGE(buf ^ 1, it + 1);
        asm volatile("s_waitcnt vmcnt(4)" ::: "memory");
        __builtin_amdgcn_sched_barrier(0);
        bf16x8 bfr0, bfr1;
        GENB(bfr0, 0);
        GENB(bfr1, 1);
        LOADEG(it + 1);
        COMPUTE(buf, bfr0, bfr1);
    }
    asm volatile("s_waitcnt vmcnt(0)" ::: "memory");
    __builtin_amdgcn_sched_barrier(0);
    {
        bf16x8 bfr0, bfr1;
        GENB(bfr0, 0);
        GENB(bfr1, 1);
        COMPUTE(1, bfr0, bfr1);
    }

    // cross-wave K-reduction (one LDS round) + residual + store.
    __syncthreads();
    float* redf = (float*)&Asm[0][0][0];   // 8192 floats = 32 KB
    #pragma unroll
    for (int i = 0; i < 4; ++i)
        #pragma unroll
        for (int t = 0; t < 2; ++t)
            *(f32x4*)&redf[((h * 8 + i * 2 + t) * 64 + l) * 4] = acc[i][t];
    __syncthreads();
    #pragma unroll
    for (int i = 0; i < 4; ++i) {
        if (i == h) {
            #pragma unroll
            for (int t = 0; t < 2; ++t) {
                f32x4 v = acc[i][t];
                #pragma unroll
                for (int s = 0; s < 4; ++s) {
                    if (s != h) {
                        f32x4 o = *(const f32x4*)&redf[((s * 8 + i * 2 + t) * 64 + l) * 4];
                        v[0] += o[0]; v[1] += o[1]; v[2] += o[2]; v[3] += o[3];
                    }
                }
                #pragma unroll
                for (int r = 0; r < 4; ++r) {
                    int c = c0 + 16 * i + g * 4 + r;
                    size_t idx = ((size_t)(b * C_DIM + c)) * N_DIM + ncol[t];
                    out[idx] = v[r] + x[idx];
                }
            }
        }
    }
    #undef STAGE
    #undef LOADEG
    #undef GENB
    #undef COMPUTE
}

// ===================== fallback path (round-1, proven) =====================

__global__ __launch_bounds__(256) void k_s12_fb(const float* __restrict__ x,
                                                const float* __restrict__ W,
                                                float* __restrict__ s1,
                                                float* __restrict__ s2) {
    int b = blockIdx.y;
    int n = blockIdx.x * 256 + threadIdx.x;
    const float* px = x + ((size_t)b * C_DIM) * N_DIM + n;
    float a1 = 0.f, a2 = 0.f;
    #pragma unroll 4
    for (int c = 0; c < C_DIM; ++c) {
        float v = px[(size_t)c * N_DIM];
        a1 = fmaf(v, W[c], a1);
        a2 = fmaf(v, W[C_DIM + c], a2);
    }
    s1[b * N_DIM + n] = a1;
    s2[b * N_DIM + n] = a2;
}

__global__ __launch_bounds__(256) void k_max_fb(const float* __restrict__ s1,
                                                float* __restrict__ s1max) {
    __shared__ float red[256];
    int b = blockIdx.x, tid = threadIdx.x;
    float mx = -3.4e38f;
    for (int k = tid; k < N_DIM; k += 256) mx = fmaxf(mx, s1[b * N_DIM + k]);
    red[tid] = mx;
    __syncthreads();
    for (int s = 128; s > 0; s >>= 1) {
        if (tid < s) red[tid] = fmaxf(red[tid], red[tid + s]);
        __syncthreads();
    }
    if (tid == 0) s1max[b] = red[0];
}

__global__ __launch_bounds__(256) void k_z_fb(const float* __restrict__ s1,
                                              const float* __restrict__ s2,
                                              const float* __restrict__ s1max,
                                              float* __restrict__ mArr,
                                              float* __restrict__ rZ) {
    int w = threadIdx.x >> 6, l = threadIdx.x & 63;
    int row = blockIdx.x * 4 + w;
    int b = row >> 12;
    const float* s1b = s1 + b * N_DIM;
    float s2n = s2[row];
    float mn = lrelu(s2n + s1max[b]);
    float sum = 0.f;
    for (int k = l; k < N_DIM; k += 64)
        sum += __expf(lrelu(s2n + s1b[k]) - mn);
    #pragma unroll
    for (int off = 32; off > 0; off >>= 1) sum += __shfl_down(sum, off);
    if (l == 0) { mArr[row] = mn; rZ[row] = 1.f / sum; }
}

__global__ __launch_bounds__(256) void k_gemm_fb(const float* __restrict__ x,
                                                 const float* __restrict__ s1,
                                                 const float* __restrict__ s2,
                                                 const float* __restrict__ mArr,
                                                 const float* __restrict__ rZ,
                                                 float* __restrict__ out) {
    const int b = blockIdx.z, c0 = blockIdx.y * 64, n0 = blockIdx.x * 128;
    const int tid = threadIdx.x;
    const int w = tid >> 6, l = tid & 63, lr = l & 15, g = l >> 4;
    const float* pb = x + (size_t)b * C_DIM * N_DIM;
    const float* s1b = s1 + b * N_DIM;
    int ncol[2]; float s2c[2], mc[2], rzc[2];
    #pragma unroll
    for (int t = 0; t < 2; ++t) {
        int n = n0 + w * 32 + t * 16 + lr;
        ncol[t] = n; s2c[t] = s2[b * N_DIM + n];
        mc[t] = mArr[b * N_DIM + n]; rzc[t] = rZ[b * N_DIM + n];
    }
    f32x4 acc[4][2];
    #pragma unroll
    for (int i = 0; i < 4; ++i)
        #pragma unroll
        for (int t = 0; t < 2; ++t) acc[i][t] = (f32x4){0.f, 0.f, 0.f, 0.f};
    for (int k0 = 0; k0 < N_DIM; k0 += 32) {
        const int kk = k0 + g * 8;
        f32x4 s1lo = *(const f32x4*)(s1b + kk);
        f32x4 s1hi = *(const f32x4*)(s1b + kk + 4);
        bf16x8 afrag[4];
        #pragma unroll
        for (int i = 0; i < 4; ++i) {
            const float* ap = pb + (size_t)(c0 + i * 16 + lr) * N_DIM + kk;
            f32x4 lo = *(const f32x4*)ap;
            f32x4 hi = *(const f32x4*)(ap + 4);
            bfv8 av;
            #pragma unroll
            for (int j = 0; j < 4; ++j) { av[j] = (__bf16)lo[j]; av[j + 4] = (__bf16)hi[j]; }
            afrag[i] = __builtin_bit_cast(bf16x8, av);
        }
        bf16x8 bfrag[2];
        #pragma unroll
        for (int t = 0; t < 2; ++t) {
            bfv8 qv;
            #pragma unroll
            for (int j = 0; j < 8; ++j) {
                float s1k = (j < 4) ? s1lo[j] : s1hi[j - 4];
                float q = __expf(lrelu(s2c[t] + s1k) - mc[t]) * rzc[t];
                qv[j] = (__bf16)q;
            }
            bfrag[t] = __builtin_bit_cast(bf16x8, qv);
        }
        #pragma unroll
        for (int i = 0; i < 4; ++i)
            #pragma unroll
            for (int t = 0; t < 2; ++t)
                acc[i][t] = __builtin_amdgcn_mfma_f32_16x16x32_bf16(
                    afrag[i], bfrag[t], acc[i][t], 0, 0, 0);
    }
    #pragma unroll
    for (int i = 0; i < 4; ++i)
        #pragma unroll
        for (int t = 0; t < 2; ++t)
            #pragma unroll
            for (int r = 0; r < 4; ++r) {
                int c = c0 + i * 16 + g * 4 + r;
                size_t idx = ((size_t)(b * C_DIM + c)) * N_DIM + ncol[t];
                out[idx] = acc[i][t][r] + x[idx];
            }
}

// ===================== launch =====================

extern "C" void kernel_launch(void* const* d_in, const int* in_sizes, int n_in,
                              void* d_out, int out_size, void* d_ws, size_t ws_size,
                              hipStream_t stream) {
    const float* x = (const float*)d_in[0];
    const float* W = (const float*)d_in[1];
    float* out = (float*)d_out;
    float* ws = (float*)d_ws;

    const size_t o_s1p = 0, o_s2p = 40960, o_s2 = 81920, o_Ek = 90112,
                 o_Gk = 98304, o_Fz = 106496, o_Hz = 114688, o_mx = 122880,
                 o_xb = 122888;
    const size_t need = o_xb * 4 + (size_t)2 * C_DIM * N_DIM * 2;

    if (ws_size >= need) {
        float* s1p = ws + o_s1p;
        float* s2p = ws + o_s2p;
        float* s2  = ws + o_s2;
        float* Ekf = ws + o_Ek;
        float* Gkf = ws + o_Gk;
        float* Fz  = ws + o_Fz;
        float* Hz  = ws + o_Hz;
        float* s1max = ws + o_mx;
        short* xb = (short*)(ws + o_xb);
        k_s12 <<<dim3(64, 5, 2), 256, 0, stream>>>(x, W, s1p, s2p, xb);
        k_fold<<<2, 1024, 0, stream>>>(s1p, s2p, s2, Ekf, Gkf, s1max);
        k_z   <<<dim3(256, 2), 256, 0, stream>>>(s2, s1max, Ekf, Gkf, Fz, Hz);
        k_gemm<<<dim3(128, 5, 2), 256, 0, stream>>>(xb, x, Ekf, Gkf, Fz, Hz, out);
    } else {
        float* s1 = ws;
        float* s2 = ws + 8192;
        float* mArr = ws + 16384;
        float* rZ = ws + 24576;
        float* s1max = ws + 32768;
        k_s12_fb<<<dim3(N_DIM / 256, 2), 256, 0, stream>>>(x, W, s1, s2);
        k_max_fb<<<2, 256, 0, stream>>>(s1, s1max);
        k_z_fb<<<(2 * N_DIM) / 4, 256, 0, stream>>>(s1, s2, s1max, mArr, rZ);
        k_gemm_fb<<<dim3(N_DIM / 128, C_DIM / 64, 2), 256, 0, stream>>>(x, s1, s2, mArr, rZ, out);
    }
}

// Round 5
// 81.830 us; speedup vs baseline: 1.1254x; 1.1254x over previous
//
#include <hip/hip_runtime.h>
#include <hip/hip_bf16.h>

#define C_DIM 320
#define N_DIM 4096
#define NEG 0.01f

typedef float f32x4 __attribute__((ext_vector_type(4)));
typedef float f32x2 __attribute__((ext_vector_type(2)));
typedef short bf16x8 __attribute__((ext_vector_type(8)));
typedef __bf16 bfv8 __attribute__((ext_vector_type(8)));

__device__ __forceinline__ float lrelu(float e) { return fmaxf(e, NEG * e); }

__device__ __forceinline__ void gload_lds16(const void* g, void* l) {
    __builtin_amdgcn_global_load_lds(
        (const __attribute__((address_space(1))) void*)g,
        (__attribute__((address_space(3))) void*)l, 16, 0, 0);
}

// ============================================================
// NEW fast path: sorted-prefix algorithm (no GEMM at all)
// out[c,n] = fz[n]*SE_suffix(Jn)[c] + hz[n]*SG_prefix(Jn)[c] + P[c,n]
// where k sorted ascending by s1; Jn = lower_bound(S, -s2[n]).
// ============================================================

// s1/s2 full dot products + transposed copy xT[b][n][c]
__global__ __launch_bounds__(256) void k_pre(const float* __restrict__ x,
                                             const float* __restrict__ W,
                                             float* __restrict__ s1,
                                             float* __restrict__ s2,
                                             float* __restrict__ xT) {
    __shared__ float r1[4][64], r2[4][64];
    __shared__ float tw[4][64][17];
    const int b = blockIdx.y;
    const int nl = threadIdx.x & 63, cw = threadIdx.x >> 6;
    const int n0 = blockIdx.x * 64;
    const int n = n0 + nl;
    float a1 = 0.f, a2 = 0.f;
    for (int sub = 0; sub < 5; ++sub) {
        const int cb = cw * 80 + sub * 16;
        #pragma unroll
        for (int cc = 0; cc < 16; ++cc) {
            const int c = cb + cc;
            float v = x[((size_t)(b * C_DIM + c)) * N_DIM + n];
            a1 = fmaf(v, W[c], a1);
            a2 = fmaf(v, W[C_DIM + c], a2);
            tw[cw][nl][cc] = v;
        }
        #pragma unroll
        for (int rr = 0; rr < 4; ++rr) {
            const int nlo = rr * 16 + (nl >> 2);
            const int c4 = (nl & 3) * 4;
            f32x4 vv;
            #pragma unroll
            for (int q = 0; q < 4; ++q) vv[q] = tw[cw][nlo][c4 + q];
            *(f32x4*)&xT[((size_t)b * N_DIM + n0 + nlo) * C_DIM + cb + c4] = vv;
        }
    }
    r1[cw][nl] = a1; r2[cw][nl] = a2;
    __syncthreads();
    if (threadIdx.x < 64) {
        s1[b * N_DIM + n] = r1[0][nl] + r1[1][nl] + r1[2][nl] + r1[3][nl];
        s2[b * N_DIM + n] = r2[0][nl] + r2[1][nl] + r2[2][nl] + r2[3][nl];
    }
}

// partial ranks: pcnt[b][chunk][k] = #{k' in chunk: s1[k'] < s1[k] (tie: k'<k)}
__global__ __launch_bounds__(256) void k_rank(const float* __restrict__ s1,
                                              int* __restrict__ pcnt) {
    __shared__ float ch[512];
    const int chunk = blockIdx.x, kt = blockIdx.y, b = blockIdx.z;
    const int tid = threadIdx.x;
    const int kbase = chunk * 512;
    ch[tid] = s1[b * N_DIM + kbase + tid];
    ch[tid + 256] = s1[b * N_DIM + kbase + tid + 256];
    __syncthreads();
    const int k = kt * 256 + tid;
    const float v = s1[b * N_DIM + k];
    int cnt = 0;
    #pragma unroll 8
    for (int i = 0; i < 512; ++i) {
        float sv = ch[i];
        int kc = kbase + i;
        cnt += (sv < v || (sv == v && kc < k)) ? 1 : 0;
    }
    pcnt[(b * 8 + chunk) * N_DIM + k] = cnt;
}

// scatter into sorted order + exclusive prefix scans EP/GP of exp(S), exp(.01 S)
__global__ __launch_bounds__(1024) void k_sct(const float* __restrict__ s1,
                                              const int* __restrict__ pcnt,
                                              float* __restrict__ Sg,
                                              int* __restrict__ idxg,
                                              float* __restrict__ EP,
                                              float* __restrict__ GP) {
    __shared__ float sv[4096];
    __shared__ int si[4096];
    __shared__ float wte[16], wtg[16];
    const int b = blockIdx.x, tid = threadIdx.x;
    #pragma unroll
    for (int q = 0; q < 4; ++q) {
        const int k = q * 1024 + tid;
        int r = 0;
        #pragma unroll
        for (int c = 0; c < 8; ++c) r += pcnt[(b * 8 + c) * N_DIM + k];
        sv[r] = s1[b * N_DIM + k];
        si[r] = k;
    }
    __syncthreads();
    const int j0 = tid * 4;
    float pe[4], pg[4];
    {
        float v0 = sv[j0], v1 = sv[j0 + 1], v2 = sv[j0 + 2], v3 = sv[j0 + 3];
        float e0 = __expf(v0), e1 = __expf(v1), e2 = __expf(v2), e3 = __expf(v3);
        float g0 = __expf(NEG * v0), g1 = __expf(NEG * v1);
        float g2 = __expf(NEG * v2), g3 = __expf(NEG * v3);
        pe[0] = e0; pe[1] = pe[0] + e1; pe[2] = pe[1] + e2; pe[3] = pe[2] + e3;
        pg[0] = g0; pg[1] = pg[0] + g1; pg[2] = pg[1] + g2; pg[3] = pg[2] + g3;
    }
    const float te = pe[3], tg = pg[3];
    const int lane = tid & 63, wid = tid >> 6;
    float ie = te, ig = tg;
    #pragma unroll
    for (int o = 1; o < 64; o <<= 1) {
        float ue = __shfl_up(ie, o);
        float ug = __shfl_up(ig, o);
        if (lane >= o) { ie += ue; ig += ug; }
    }
    if (lane == 63) { wte[wid] = ie; wtg[wid] = ig; }
    __syncthreads();
    float oe = 0.f, og = 0.f;
    for (int wq = 0; wq < wid; ++wq) { oe += wte[wq]; og += wtg[wq]; }
    const float be = oe + ie - te, bg = og + ig - tg;
    #pragma unroll
    for (int i = 0; i < 4; ++i) {
        EP[b * 4097 + j0 + i] = be + (i ? pe[i - 1] : 0.f);
        GP[b * 4097 + j0 + i] = bg + (i ? pg[i - 1] : 0.f);
    }
    if (tid == 1023) {
        EP[b * 4097 + 4096] = oe + ie;
        GP[b * 4097 + 4096] = og + ig;
    }
    #pragma unroll
    for (int q = 0; q < 4; ++q) {
        const int j = q * 1024 + tid;
        Sg[b * N_DIM + j] = sv[j];
        idxg[b * N_DIM + j] = si[j];
    }
}

// per n: Jn = lower_bound(S, -s2), Z via EP/GP, fz=F/Z, hz=H/Z
__global__ __launch_bounds__(256) void k_jz(const float* __restrict__ s2,
                                            const float* __restrict__ Sg,
                                            const float* __restrict__ EP,
                                            const float* __restrict__ GP,
                                            int* __restrict__ JnA,
                                            float* __restrict__ fzA,
                                            float* __restrict__ hzA) {
    __shared__ float Sl[4096];
    const int b = blockIdx.y, tid = threadIdx.x;
    for (int i = tid; i < 4096; i += 256) Sl[i] = Sg[b * N_DIM + i];
    __syncthreads();
    const int n = blockIdx.x * 256 + tid;
    const float s2n = s2[b * N_DIM + n];
    const float smax = Sl[4095];
    const float mn = lrelu(s2n + smax);
    const float F = __expf(s2n - mn), H = __expf(NEG * s2n - mn);
    const float t = -s2n;
    int lo = 0, hi = 4096;
    while (lo < hi) {
        int mid = (lo + hi) >> 1;
        if (Sl[mid] < t) lo = mid + 1; else hi = mid;
    }
    const float EPt = EP[b * 4097 + 4096];
    const float suf = EPt - EP[b * 4097 + lo];
    const float pre = GP[b * 4097 + lo];
    const float rz = 1.f / (F * suf + H * pre);
    JnA[b * N_DIM + n] = lo;
    fzA[b * N_DIM + n] = F * rz;
    hzA[b * N_DIM + n] = H * rz;
}

// per (b, c-group, j-tile of 256): local inclusive prefixes of P*e^{S}, P*e^{.01S}
__global__ __launch_bounds__(64) void k_prefix(const float* __restrict__ xT,
                                               const float* __restrict__ Sg,
                                               const int* __restrict__ idxg,
                                               float* __restrict__ Tloc,
                                               float* __restrict__ tot) {
    const int jt = blockIdx.x, cg = blockIdx.y, b = blockIdx.z;
    const int l = threadIdx.x;
    const int c = cg * 64 + l;
    const float* xTb = xT + (size_t)b * N_DIM * C_DIM;
    float se = 0.f, sg = 0.f;
    #pragma unroll 4
    for (int j = 0; j < 256; ++j) {
        const int jj = jt * 256 + j;
        const float sval = Sg[b * N_DIM + jj];
        const int kidx = idxg[b * N_DIM + jj];
        const float e = __expf(sval), g = __expf(NEG * sval);
        const float xv = xTb[(size_t)kidx * C_DIM + c];
        se = fmaf(xv, e, se);
        sg = fmaf(xv, g, sg);
        *(f32x2*)&Tloc[(((size_t)b * N_DIM + jj) * C_DIM + c) * 2] = (f32x2){se, sg};
    }
    *(f32x2*)&tot[((b * 16 + jt) * C_DIM + c) * 2] = (f32x2){se, sg};
}

// exclusive scan of 16 tile totals per (b,c) + grand total in slot 16
__global__ __launch_bounds__(320) void k_scan(const float* __restrict__ tot,
                                              float* __restrict__ off) {
    const int b = blockIdx.x, c = threadIdx.x;
    float ae = 0.f, ag = 0.f;
    #pragma unroll
    for (int jt = 0; jt < 16; ++jt) {
        off[((b * 17 + jt) * C_DIM + c) * 2 + 0] = ae;
        off[((b * 17 + jt) * C_DIM + c) * 2 + 1] = ag;
        f32x2 t = *(const f32x2*)&tot[((b * 16 + jt) * C_DIM + c) * 2];
        ae += t[0]; ag += t[1];
    }
    off[((b * 17 + 16) * C_DIM + c) * 2 + 0] = ae;
    off[((b * 17 + 16) * C_DIM + c) * 2 + 1] = ag;
}

// lookup + transpose + residual
__global__ __launch_bounds__(256) void k_out(const float* __restrict__ x,
                                             const float* __restrict__ Tloc,
                                             const float* __restrict__ off,
                                             const int* __restrict__ JnA,
                                             const float* __restrict__ fzA,
                                             const float* __restrict__ hzA,
                                             float* __restrict__ out) {
    __shared__ float offl[17][64][2];
    __shared__ float tile[64][65];
    const int b = blockIdx.z, cg = blockIdx.y, n0 = blockIdx.x * 64;
    const int tid = threadIdx.x, w = tid >> 6, l = tid & 63;
    const int c0 = cg * 64;
    for (int i = tid; i < 17 * 64; i += 256) {
        const int jt = i >> 6, cl = i & 63;
        f32x2 o = *(const f32x2*)&off[((b * 17 + jt) * C_DIM + c0 + cl) * 2];
        offl[jt][cl][0] = o[0];
        offl[jt][cl][1] = o[1];
    }
    __syncthreads();
    for (int i = 0; i < 16; ++i) {
        const int nl = w * 16 + i, n = n0 + nl;
        const int Jn = JnA[b * N_DIM + n];
        const float fzv = fzA[b * N_DIM + n], hzv = hzA[b * N_DIM + n];
        const int jt = Jn >> 8, jl = Jn & 255;
        float se = 0.f, sg = 0.f;
        if (jl != 0) {
            f32x2 t = *(const f32x2*)&Tloc[(((size_t)b * N_DIM + Jn - 1) * C_DIM + c0 + l) * 2];
            se = t[0]; sg = t[1];
        }
        const float se_ex = offl[jt][l][0] + se;
        const float sg_ex = offl[jt][l][1] + sg;
        tile[l][nl] = fzv * (offl[16][l][0] - se_ex) + hzv * sg_ex;
    }
    __syncthreads();
    const int row = tid >> 2, nseg = (tid & 3) * 16;
    const size_t gidx = ((size_t)(b * C_DIM + c0 + row)) * N_DIM + n0 + nseg;
    #pragma unroll
    for (int i2 = 0; i2 < 16; i2 += 4) {
        f32x4 xv = *(const f32x4*)&x[gidx + i2];
        f32x4 o;
        #pragma unroll
        for (int q = 0; q < 4; ++q) o[q] = tile[row][nseg + i2 + q] + xv[q];
        *(f32x4*)&out[gidx + i2] = o;
    }
}

// ============================================================
// MID fallback: round-3 path (proven 75 us)
// ============================================================

__global__ __launch_bounds__(256) void k_s12(const float* __restrict__ x,
                                             const float* __restrict__ W,
                                             float* __restrict__ s1p,
                                             float* __restrict__ s2p,
                                             short* __restrict__ xb) {
    const int b = blockIdx.z, cb = blockIdx.y;
    const int nl = threadIdx.x & 63, cw = threadIdx.x >> 6;
    const int n = blockIdx.x * 64 + nl;
    const int cbase = cb * 64 + cw * 16;
    const float* px = x + ((size_t)b * C_DIM + cbase) * N_DIM + n;
    short* pxb = xb + ((size_t)b * C_DIM + cbase) * N_DIM + n;
    const float* w1 = W + cbase;
    const float* w2 = W + C_DIM + cbase;
    float a1 = 0.f, a2 = 0.f;
    #pragma unroll
    for (int cc = 0; cc < 16; ++cc) {
        float v = px[(size_t)cc * N_DIM];
        a1 = fmaf(v, w1[cc], a1);
        a2 = fmaf(v, w2[cc], a2);
        __hip_bfloat16 hv = __float2bfloat16(v);
        pxb[(size_t)cc * N_DIM] = *(short*)&hv;
    }
    __shared__ float r1[4][64], r2[4][64];
    r1[cw][nl] = a1; r2[cw][nl] = a2;
    __syncthreads();
    if (threadIdx.x < 64) {
        s1p[((size_t)b * 5 + cb) * N_DIM + n] = r1[0][nl] + r1[1][nl] + r1[2][nl] + r1[3][nl];
        s2p[((size_t)b * 5 + cb) * N_DIM + n] = r2[0][nl] + r2[1][nl] + r2[2][nl] + r2[3][nl];
    }
}

__global__ __launch_bounds__(1024) void k_fold(const float* __restrict__ s1p,
                                               const float* __restrict__ s2p,
                                               float* __restrict__ s2,
                                               float* __restrict__ Ekf,
                                               float* __restrict__ Gkf,
                                               float* __restrict__ s1max) {
    const int b = blockIdx.x, tid = threadIdx.x;
    __shared__ float md[1024];
    float mx = -3.4e38f;
    for (int n = tid; n < N_DIM; n += 1024) {
        float v1 = 0.f, v2 = 0.f;
        #pragma unroll
        for (int cb = 0; cb < 5; ++cb) {
            v1 += s1p[((size_t)b * 5 + cb) * N_DIM + n];
            v2 += s2p[((size_t)b * 5 + cb) * N_DIM + n];
        }
        s2[b * N_DIM + n] = v2;
        Ekf[b * N_DIM + n] = __expf(v1);
        Gkf[b * N_DIM + n] = __expf(NEG * v1);
        mx = fmaxf(mx, v1);
    }
    md[tid] = mx;
    __syncthreads();
    for (int s = 512; s > 0; s >>= 1) {
        if (tid < s) md[tid] = fmaxf(md[tid], md[tid + s]);
        __syncthreads();
    }
    if (tid == 0) s1max[b] = md[0];
}

__global__ __launch_bounds__(256) void k_z(const float* __restrict__ s2,
                                           const float* __restrict__ s1max,
                                           const float* __restrict__ Ekf,
                                           const float* __restrict__ Gkf,
                                           float* __restrict__ Fz,
                                           float* __restrict__ Hz) {
    __shared__ __align__(16) float Els[4096], Gls[4096];
    const int b = blockIdx.y, tid = threadIdx.x;
    const int w = tid >> 6, l = tid & 63;
    const float* Eb = Ekf + b * N_DIM;
    const float* Gb = Gkf + b * N_DIM;
    #pragma unroll
    for (int i = 0; i < 4; ++i) {
        int chn = i * 256 + tid;
        *(f32x4*)&Els[chn * 4] = *(const f32x4*)&Eb[chn * 4];
        *(f32x4*)&Gls[chn * 4] = *(const f32x4*)&Gb[chn * 4];
    }
    __syncthreads();
    float smax = s1max[b];
    #pragma unroll
    for (int rr = 0; rr < 4; ++rr) {
        int row = b * N_DIM + blockIdx.x * 16 + w * 4 + rr;
        float s2n = s2[row];
        float mn = lrelu(s2n + smax);
        float F = __expf(s2n - mn), H = __expf(NEG * s2n - mn);
        float sum = 0.f;
        #pragma unroll 4
        for (int i = 0; i < 16; ++i) {
            int k = i * 256 + l * 4;
            f32x4 e = *(const f32x4*)&Els[k];
            f32x4 gg = *(const f32x4*)&Gls[k];
            #pragma unroll
            for (int j = 0; j < 4; ++j) sum += fmaxf(e[j] * F, gg[j] * H);
        }
        #pragma unroll
        for (int off = 32; off > 0; off >>= 1) sum += __shfl_down(sum, off);
        if (l == 0) {
            float rz = 1.f / sum;
            Fz[row] = F * rz;
            Hz[row] = H * rz;
        }
    }
}

__global__ __launch_bounds__(128) void k_gemm(const short* __restrict__ xb,
                                              const float* __restrict__ x,
                                              const float* __restrict__ Ekf,
                                              const float* __restrict__ Gkf,
                                              const float* __restrict__ Fz,
                                              const float* __restrict__ Hz,
                                              float* __restrict__ out) {
    __shared__ __align__(16) short Asm[2][2][4096];
    __shared__ __align__(16) float EGs[2][2][256];

    const int b = blockIdx.z, c0 = blockIdx.y * 64, n0 = blockIdx.x * 64;
    const int tid = threadIdx.x;
    const int h = tid >> 6, l = tid & 63, lr = l & 15, g = l >> 4;
    const short* xbp = xb + (size_t)b * C_DIM * N_DIM + h * 2048;
    const float* Eb = Ekf + b * N_DIM + h * 2048;
    const float* Gb = Gkf + b * N_DIM + h * 2048;

    int ncol[4]; float fz[4], hz[4];
    #pragma unroll
    for (int t = 0; t < 4; ++t) {
        int n = n0 + t * 16 + lr;
        ncol[t] = n;
        fz[t] = Fz[b * N_DIM + n];
        hz[t] = Hz[b * N_DIM + n];
    }

    f32x4 acc[4][4];
    #pragma unroll
    for (int i = 0; i < 4; ++i)
        #pragma unroll
        for (int t = 0; t < 4; ++t) acc[i][t] = (f32x4){0.f, 0.f, 0.f, 0.f};

    auto stageA = [&](int buf, int it) {
        #pragma unroll
        for (int i = 0; i < 8; ++i) {
            int row = i * 8 + (l >> 3);
            int c8 = (l & 7) ^ (row & 7);
            gload_lds16(xbp + (size_t)(c0 + row) * N_DIM + it * 64 + c8 * 8,
                        &Asm[h][buf][i * 512]);
        }
    };
    auto stageEG = [&](int buf, int it) {
        int lm = l & 31;
        const float* p = (lm < 16) ? (Eb + it * 64 + lm * 4)
                                   : (Gb + it * 64 + (lm - 16) * 4);
        gload_lds16(p, &EGs[h][buf][0]);
    };

    stageA(0, 0); stageEG(0, 0);
    for (int it = 0; it < 32; ++it) {
        const int buf = it & 1;
        if (it < 31) {
            stageA(buf ^ 1, it + 1);
            stageEG(buf ^ 1, it + 1);
            asm volatile("s_waitcnt vmcnt(9)" ::: "memory");
        } else {
            asm volatile("s_waitcnt vmcnt(0)" ::: "memory");
        }
        __builtin_amdgcn_sched_barrier(0);
        #pragma unroll
        for (int s = 0; s < 2; ++s) {
            const int kk = s * 32 + g * 8;
            f32x4 e0 = *(const f32x4*)&EGs[h][buf][kk];
            f32x4 e1 = *(const f32x4*)&EGs[h][buf][kk + 4];
            f32x4 g0 = *(const f32x4*)&EGs[h][buf][64 + kk];
            f32x4 g1 = *(const f32x4*)&EGs[h][buf][64 + kk + 4];
            bf16x8 afr[4];
            #pragma unroll
            for (int i = 0; i < 4; ++i) {
                int row = 16 * i + lr;
                int idx = row * 64 + (((4 * s + g) ^ (row & 7)) * 8);
                afr[i] = *(const bf16x8*)&Asm[h][buf][idx];
            }
            bf16x8 bfr[4];
            #pragma unroll
            for (int t = 0; t < 4; ++t) {
                bfv8 qv;
                #pragma unroll
                for (int j = 0; j < 4; ++j) {
                    qv[j]     = (__bf16)fmaxf(e0[j] * fz[t], g0[j] * hz[t]);
                    qv[j + 4] = (__bf16)fmaxf(e1[j] * fz[t], g1[j] * hz[t]);
                }
                bfr[t] = __builtin_bit_cast(bf16x8, qv);
            }
            #pragma unroll
            for (int i = 0; i < 4; ++i)
                #pragma unroll
                for (int t = 0; t < 4; ++t)
                    acc[i][t] = __builtin_amdgcn_mfma_f32_16x16x32_bf16(
                        afr[i], bfr[t], acc[i][t], 0, 0, 0);
        }
    }

    __syncthreads();
    float* red = (float*)&Asm[0][0][0];
    if (h == 1) {
        #pragma unroll
        for (int i = 0; i < 4; ++i)
            #pragma unroll
            for (int t = 0; t < 4; ++t)
                #pragma unroll
                for (int r = 0; r < 4; ++r)
                    red[((i * 4 + t) * 4 + r) * 64 + l] = acc[i][t][r];
    }
    __syncthreads();
    if (h == 0) {
        #pragma unroll
        for (int i = 0; i < 4; ++i)
            #pragma unroll
            for (int t = 0; t < 4; ++t)
                #pragma unroll
                for (int r = 0; r < 4; ++r) {
                    float v = acc[i][t][r] + red[((i * 4 + t) * 4 + r) * 64 + l];
                    int c = c0 + 16 * i + g * 4 + r;
                    size_t idx = ((size_t)(b * C_DIM + c)) * N_DIM + ncol[t];
                    out[idx] = v + x[idx];
                }
    }
}

// ============================================================
// LAST fallback: round-1 path (proven)
// ============================================================

__global__ __launch_bounds__(256) void k_s12_fb(const float* __restrict__ x,
                                                const float* __restrict__ W,
                                                float* __restrict__ s1,
                                                float* __restrict__ s2) {
    int b = blockIdx.y;
    int n = blockIdx.x * 256 + threadIdx.x;
    const float* px = x + ((size_t)b * C_DIM) * N_DIM + n;
    float a1 = 0.f, a2 = 0.f;
    #pragma unroll 4
    for (int c = 0; c < C_DIM; ++c) {
        float v = px[(size_t)c * N_DIM];
        a1 = fmaf(v, W[c], a1);
        a2 = fmaf(v, W[C_DIM + c], a2);
    }
    s1[b * N_DIM + n] = a1;
    s2[b * N_DIM + n] = a2;
}

__global__ __launch_bounds__(256) void k_max_fb(const float* __restrict__ s1,
                                                float* __restrict__ s1max) {
    __shared__ float red[256];
    int b = blockIdx.x, tid = threadIdx.x;
    float mx = -3.4e38f;
    for (int k = tid; k < N_DIM; k += 256) mx = fmaxf(mx, s1[b * N_DIM + k]);
    red[tid] = mx;
    __syncthreads();
    for (int s = 128; s > 0; s >>= 1) {
        if (tid < s) red[tid] = fmaxf(red[tid], red[tid + s]);
        __syncthreads();
    }
    if (tid == 0) s1max[b] = red[0];
}

__global__ __launch_bounds__(256) void k_z_fb(const float* __restrict__ s1,
                                              const float* __restrict__ s2,
                                              const float* __restrict__ s1max,
                                              float* __restrict__ mArr,
                                              float* __restrict__ rZ) {
    int w = threadIdx.x >> 6, l = threadIdx.x & 63;
    int row = blockIdx.x * 4 + w;
    int b = row >> 12;
    const float* s1b = s1 + b * N_DIM;
    float s2n = s2[row];
    float mn = lrelu(s2n + s1max[b]);
    float sum = 0.f;
    for (int k = l; k < N_DIM; k += 64)
        sum += __expf(lrelu(s2n + s1b[k]) - mn);
    #pragma unroll
    for (int off = 32; off > 0; off >>= 1) sum += __shfl_down(sum, off);
    if (l == 0) { mArr[row] = mn; rZ[row] = 1.f / sum; }
}

__global__ __launch_bounds__(256) void k_gemm_fb(const float* __restrict__ x,
                                                 const float* __restrict__ s1,
                                                 const float* __restrict__ s2,
                                                 const float* __restrict__ mArr,
                                                 const float* __restrict__ rZ,
                                                 float* __restrict__ out) {
    const int b = blockIdx.z, c0 = blockIdx.y * 64, n0 = blockIdx.x * 128;
    const int tid = threadIdx.x;
    const int w = tid >> 6, l = tid & 63, lr = l & 15, g = l >> 4;
    const float* pb = x + (size_t)b * C_DIM * N_DIM;
    const float* s1b = s1 + b * N_DIM;
    int ncol[2]; float s2c[2], mc[2], rzc[2];
    #pragma unroll
    for (int t = 0; t < 2; ++t) {
        int n = n0 + w * 32 + t * 16 + lr;
        ncol[t] = n; s2c[t] = s2[b * N_DIM + n];
        mc[t] = mArr[b * N_DIM + n]; rzc[t] = rZ[b * N_DIM + n];
    }
    f32x4 acc[4][2];
    #pragma unroll
    for (int i = 0; i < 4; ++i)
        #pragma unroll
        for (int t = 0; t < 2; ++t) acc[i][t] = (f32x4){0.f, 0.f, 0.f, 0.f};
    for (int k0 = 0; k0 < N_DIM; k0 += 32) {
        const int kk = k0 + g * 8;
        f32x4 s1lo = *(const f32x4*)(s1b + kk);
        f32x4 s1hi = *(const f32x4*)(s1b + kk + 4);
        bf16x8 afrag[4];
        #pragma unroll
        for (int i = 0; i < 4; ++i) {
            const float* ap = pb + (size_t)(c0 + i * 16 + lr) * N_DIM + kk;
            f32x4 lo = *(const f32x4*)ap;
            f32x4 hi = *(const f32x4*)(ap + 4);
            bfv8 av;
            #pragma unroll
            for (int j = 0; j < 4; ++j) { av[j] = (__bf16)lo[j]; av[j + 4] = (__bf16)hi[j]; }
            afrag[i] = __builtin_bit_cast(bf16x8, av);
        }
        bf16x8 bfrag[2];
        #pragma unroll
        for (int t = 0; t < 2; ++t) {
            bfv8 qv;
            #pragma unroll
            for (int j = 0; j < 8; ++j) {
                float s1k = (j < 4) ? s1lo[j] : s1hi[j - 4];
                float q = __expf(lrelu(s2c[t] + s1k) - mc[t]) * rzc[t];
                qv[j] = (__bf16)q;
            }
            bfrag[t] = __builtin_bit_cast(bf16x8, qv);
        }
        #pragma unroll
        for (int i = 0; i < 4; ++i)
            #pragma unroll
            for (int t = 0; t < 2; ++t)
                acc[i][t] = __builtin_amdgcn_mfma_f32_16x16x32_bf16(
                    afrag[i], bfrag[t], acc[i][t], 0, 0, 0);
    }
    #pragma unroll
    for (int i = 0; i < 4; ++i)
        #pragma unroll
        for (int t = 0; t < 2; ++t)
            #pragma unroll
            for (int r = 0; r < 4; ++r) {
                int c = c0 + i * 16 + g * 4 + r;
                size_t idx = ((size_t)(b * C_DIM + c)) * N_DIM + ncol[t];
                out[idx] = acc[i][t][r] + x[idx];
            }
}

// ============================================================
// launch
// ============================================================

extern "C" void kernel_launch(void* const* d_in, const int* in_sizes, int n_in,
                              void* d_out, int out_size, void* d_ws, size_t ws_size,
                              hipStream_t stream) {
    const float* x = (const float*)d_in[0];
    const float* W = (const float*)d_in[1];
    float* out = (float*)d_out;
    float* ws = (float*)d_ws;

    // ---- new-path ws layout (float offsets) ----
    const size_t o_s1 = 0, o_s2 = 8192, o_S = 16384, o_idx = 24576,
                 o_EP = 32768, o_GP = 40968, o_Jn = 49168, o_fz = 57360,
                 o_hz = 65552, o_pc = 73744, o_tot = 139280, o_off = 159760,
                 o_xT = 181520, o_Tl = 2802960, o_end = 8045840;
    const size_t need_new = o_end * 4;

    // ---- mid-path (round-3) ws layout ----
    const size_t m_s1p = 0, m_s2p = 40960, m_s2 = 81920, m_Ek = 90112,
                 m_Gk = 98304, m_Fz = 106496, m_Hz = 114688, m_mx = 122880,
                 m_xb = 122888;
    const size_t need_mid = m_xb * 4 + (size_t)2 * C_DIM * N_DIM * 2;

    if (ws_size >= need_new) {
        float* s1 = ws + o_s1;
        float* s2 = ws + o_s2;
        float* Sg = ws + o_S;
        int*   idxg = (int*)(ws + o_idx);
        float* EP = ws + o_EP;
        float* GP = ws + o_GP;
        int*   JnA = (int*)(ws + o_Jn);
        float* fzA = ws + o_fz;
        float* hzA = ws + o_hz;
        int*   pcnt = (int*)(ws + o_pc);
        float* tot = ws + o_tot;
        float* off = ws + o_off;
        float* xT = ws + o_xT;
        float* Tloc = ws + o_Tl;

        k_pre   <<<dim3(64, 2), 256, 0, stream>>>(x, W, s1, s2, xT);
        k_rank  <<<dim3(8, 16, 2), 256, 0, stream>>>(s1, pcnt);
        k_sct   <<<2, 1024, 0, stream>>>(s1, pcnt, Sg, idxg, EP, GP);
        k_jz    <<<dim3(16, 2), 256, 0, stream>>>(s2, Sg, EP, GP, JnA, fzA, hzA);
        k_prefix<<<dim3(16, 5, 2), 64, 0, stream>>>(xT, Sg, idxg, Tloc, tot);
        k_scan  <<<2, 320, 0, stream>>>(tot, off);
        k_out   <<<dim3(64, 5, 2), 256, 0, stream>>>(x, Tloc, off, JnA, fzA, hzA, out);
    } else if (ws_size >= need_mid) {
        float* s1p = ws + m_s1p;
        float* s2p = ws + m_s2p;
        float* s2  = ws + m_s2;
        float* Ekf = ws + m_Ek;
        float* Gkf = ws + m_Gk;
        float* Fz  = ws + m_Fz;
        float* Hz  = ws + m_Hz;
        float* s1max = ws + m_mx;
        short* xb = (short*)(ws + m_xb);
        k_s12 <<<dim3(64, 5, 2), 256, 0, stream>>>(x, W, s1p, s2p, xb);
        k_fold<<<2, 1024, 0, stream>>>(s1p, s2p, s2, Ekf, Gkf, s1max);
        k_z   <<<dim3(256, 2), 256, 0, stream>>>(s2, s1max, Ekf, Gkf, Fz, Hz);
        k_gemm<<<dim3(64, 5, 2), 128, 0, stream>>>(xb, x, Ekf, Gkf, Fz, Hz, out);
    } else {
        float* s1 = ws;
        float* s2 = ws + 8192;
        float* mArr = ws + 16384;
        float* rZ = ws + 24576;
        float* s1max = ws + 32768;
        k_s12_fb<<<dim3(N_DIM / 256, 2), 256, 0, stream>>>(x, W, s1, s2);
        k_max_fb<<<2, 256, 0, stream>>>(s1, s1max);
        k_z_fb<<<(2 * N_DIM) / 4, 256, 0, stream>>>(s1, s2, s1max, mArr, rZ);
        k_gemm_fb<<<dim3(N_DIM / 128, C_DIM / 64, 2), 256, 0, stream>>>(x, s1, s2, mArr, rZ, out);
    }
}

// Round 6
// 64.210 us; speedup vs baseline: 1.4343x; 1.2744x over previous
//
#include <hip/hip_runtime.h>
#include <hip/hip_bf16.h>

#define C_DIM 320
#define N_DIM 4096
#define NEG 0.01f

typedef float f32x4 __attribute__((ext_vector_type(4)));
typedef float f32x2 __attribute__((ext_vector_type(2)));
typedef short bf16x8 __attribute__((ext_vector_type(8)));
typedef __bf16 bfv8 __attribute__((ext_vector_type(8)));

__device__ __forceinline__ float lrelu(float e) { return fmaxf(e, NEG * e); }

__device__ __forceinline__ void gload_lds16(const void* g, void* l) {
    __builtin_amdgcn_global_load_lds(
        (const __attribute__((address_space(1))) void*)g,
        (__attribute__((address_space(3))) void*)l, 16, 0, 0);
}

// ============================================================
// Sorted-prefix algorithm (no GEMM):
// out[c,n] = fz[n]*(SEtot[c] - SE_ex(Jn)[c]) + hz[n]*SG_ex(Jn)[c] + P[c,n]
// k sorted ascending by s1; Jn = lower_bound(S, -s2[n]).
// Tloc holds 64-wide tile-local inclusive prefixes; off holds tile offsets.
// ============================================================

// s1/s2 dot products + transposed copy xT[b][n][c] (256B-coalesced writes)
__global__ __launch_bounds__(256) void k_pre(const float* __restrict__ x,
                                             const float* __restrict__ W,
                                             float* __restrict__ s1,
                                             float* __restrict__ s2,
                                             float* __restrict__ xT) {
    __shared__ float tile[64][65];
    __shared__ float r1[4][64], r2[4][64];
    const int b = blockIdx.y;
    const int nl = threadIdx.x & 63, cw = threadIdx.x >> 6;
    const int n0 = blockIdx.x * 64;
    const int n = n0 + nl;
    float a1 = 0.f, a2 = 0.f;
    for (int sub = 0; sub < 5; ++sub) {
        const int cb = sub * 64 + cw * 16;
        #pragma unroll
        for (int cc = 0; cc < 16; ++cc) {
            const int c = cb + cc;
            float v = x[((size_t)(b * C_DIM + c)) * N_DIM + n];
            a1 = fmaf(v, W[c], a1);
            a2 = fmaf(v, W[C_DIM + c], a2);
            tile[cw * 16 + cc][nl] = v;
        }
        __syncthreads();
        #pragma unroll
        for (int rr = 0; rr < 16; ++rr) {
            const int nloc = cw * 16 + rr;
            xT[((size_t)b * N_DIM + n0 + nloc) * C_DIM + sub * 64 + nl] = tile[nl][nloc];
        }
        __syncthreads();
    }
    r1[cw][nl] = a1; r2[cw][nl] = a2;
    __syncthreads();
    if (threadIdx.x < 64) {
        s1[b * N_DIM + n] = r1[0][nl] + r1[1][nl] + r1[2][nl] + r1[3][nl];
        s2[b * N_DIM + n] = r2[0][nl] + r2[1][nl] + r2[2][nl] + r2[3][nl];
    }
}

// partial ranks: pcnt[b][chunk][k] = #{k' in chunk: s1[k'] < s1[k] (tie: k'<k)}
__global__ __launch_bounds__(256) void k_rank(const float* __restrict__ s1,
                                              int* __restrict__ pcnt) {
    __shared__ float ch[512];
    const int chunk = blockIdx.x, kt = blockIdx.y, b = blockIdx.z;
    const int tid = threadIdx.x;
    const int kbase = chunk * 512;
    ch[tid] = s1[b * N_DIM + kbase + tid];
    ch[tid + 256] = s1[b * N_DIM + kbase + tid + 256];
    __syncthreads();
    const int k = kt * 256 + tid;
    const float v = s1[b * N_DIM + k];
    int cnt = 0;
    #pragma unroll 8
    for (int i = 0; i < 512; ++i) {
        float sv = ch[i];
        int kc = kbase + i;
        cnt += (sv < v || (sv == v && kc < k)) ? 1 : 0;
    }
    pcnt[(b * 8 + chunk) * N_DIM + k] = cnt;
}

// scatter into sorted order + EP/GP exclusive scans + sorted Eg/Gg arrays
__global__ __launch_bounds__(1024) void k_sct(const float* __restrict__ s1,
                                              const int* __restrict__ pcnt,
                                              float* __restrict__ Sg,
                                              int* __restrict__ idxg,
                                              float* __restrict__ EP,
                                              float* __restrict__ GP,
                                              float* __restrict__ Eg,
                                              float* __restrict__ Gg) {
    __shared__ float sv[4096];
    __shared__ int si[4096];
    __shared__ float wte[16], wtg[16];
    const int b = blockIdx.x, tid = threadIdx.x;
    #pragma unroll
    for (int q = 0; q < 4; ++q) {
        const int k = q * 1024 + tid;
        int r = 0;
        #pragma unroll
        for (int c = 0; c < 8; ++c) r += pcnt[(b * 8 + c) * N_DIM + k];
        sv[r] = s1[b * N_DIM + k];
        si[r] = k;
    }
    __syncthreads();
    const int j0 = tid * 4;
    float pe[4], pg[4];
    {
        float v0 = sv[j0], v1 = sv[j0 + 1], v2 = sv[j0 + 2], v3 = sv[j0 + 3];
        float e0 = __expf(v0), e1 = __expf(v1), e2 = __expf(v2), e3 = __expf(v3);
        float g0 = __expf(NEG * v0), g1 = __expf(NEG * v1);
        float g2 = __expf(NEG * v2), g3 = __expf(NEG * v3);
        Eg[b * N_DIM + j0] = e0; Eg[b * N_DIM + j0 + 1] = e1;
        Eg[b * N_DIM + j0 + 2] = e2; Eg[b * N_DIM + j0 + 3] = e3;
        Gg[b * N_DIM + j0] = g0; Gg[b * N_DIM + j0 + 1] = g1;
        Gg[b * N_DIM + j0 + 2] = g2; Gg[b * N_DIM + j0 + 3] = g3;
        pe[0] = e0; pe[1] = pe[0] + e1; pe[2] = pe[1] + e2; pe[3] = pe[2] + e3;
        pg[0] = g0; pg[1] = pg[0] + g1; pg[2] = pg[1] + g2; pg[3] = pg[2] + g3;
    }
    const float te = pe[3], tg = pg[3];
    const int lane = tid & 63, wid = tid >> 6;
    float ie = te, ig = tg;
    #pragma unroll
    for (int o = 1; o < 64; o <<= 1) {
        float ue = __shfl_up(ie, o);
        float ug = __shfl_up(ig, o);
        if (lane >= o) { ie += ue; ig += ug; }
    }
    if (lane == 63) { wte[wid] = ie; wtg[wid] = ig; }
    __syncthreads();
    float oe = 0.f, og = 0.f;
    for (int wq = 0; wq < wid; ++wq) { oe += wte[wq]; og += wtg[wq]; }
    const float be = oe + ie - te, bg = og + ig - tg;
    #pragma unroll
    for (int i = 0; i < 4; ++i) {
        EP[b * 4097 + j0 + i] = be + (i ? pe[i - 1] : 0.f);
        GP[b * 4097 + j0 + i] = bg + (i ? pg[i - 1] : 0.f);
    }
    if (tid == 1023) {
        EP[b * 4097 + 4096] = oe + ie;
        GP[b * 4097 + 4096] = og + ig;
    }
    #pragma unroll
    for (int q = 0; q < 4; ++q) {
        const int j = q * 1024 + tid;
        Sg[b * N_DIM + j] = sv[j];
        idxg[b * N_DIM + j] = si[j];
    }
}

// per n: Jn = lower_bound(S, -s2), Z via EP/GP, fz=F/Z, hz=H/Z
__global__ __launch_bounds__(256) void k_jz(const float* __restrict__ s2,
                                            const float* __restrict__ Sg,
                                            const float* __restrict__ EP,
                                            const float* __restrict__ GP,
                                            int* __restrict__ JnA,
                                            float* __restrict__ fzA,
                                            float* __restrict__ hzA) {
    __shared__ float Sl[4096];
    const int b = blockIdx.y, tid = threadIdx.x;
    for (int i = tid; i < 4096; i += 256) Sl[i] = Sg[b * N_DIM + i];
    __syncthreads();
    const int n = blockIdx.x * 256 + tid;
    const float s2n = s2[b * N_DIM + n];
    const float smax = Sl[4095];
    const float mn = lrelu(s2n + smax);
    const float F = __expf(s2n - mn), H = __expf(NEG * s2n - mn);
    const float t = -s2n;
    int lo = 0, hi = 4096;
    while (lo < hi) {
        int mid = (lo + hi) >> 1;
        if (Sl[mid] < t) lo = mid + 1; else hi = mid;
    }
    const float EPt = EP[b * 4097 + 4096];
    const float suf = EPt - EP[b * 4097 + lo];
    const float pre = GP[b * 4097 + lo];
    const float rz = 1.f / (F * suf + H * pre);
    JnA[b * N_DIM + n] = lo;
    fzA[b * N_DIM + n] = F * rz;
    hzA[b * N_DIM + n] = H * rz;
}

// per (b, cg, 64-j tile): wave-local inclusive prefixes of P*e^{S}, P*e^{.01S}
// grid (16, 5, 2) x 256 thr = 4 independent waves/block (one tile each)
__global__ __launch_bounds__(256) void k_prefix(const float* __restrict__ xT,
                                                const int* __restrict__ idxg,
                                                const float* __restrict__ Eg,
                                                const float* __restrict__ Gg,
                                                float* __restrict__ Tloc,
                                                float* __restrict__ tot) {
    const int jt4 = blockIdx.x, cg = blockIdx.y, b = blockIdx.z;
    const int w = threadIdx.x >> 6, l = threadIdx.x & 63;
    const int tile = jt4 * 4 + w;
    const int jbase = tile * 64;
    const int c = cg * 64 + l;
    const float* xTb = xT + (size_t)b * N_DIM * C_DIM;
    const float ej = Eg[b * N_DIM + jbase + l];
    const float gj = Gg[b * N_DIM + jbase + l];
    const int   ij = idxg[b * N_DIM + jbase + l];
    float se = 0.f, sg = 0.f;
    #pragma unroll 16
    for (int j = 0; j < 64; ++j) {
        const float e = __shfl(ej, j);
        const float g = __shfl(gj, j);
        const int kidx = __shfl(ij, j);
        const float xv = xTb[(size_t)kidx * C_DIM + c];
        se = fmaf(xv, e, se);
        sg = fmaf(xv, g, sg);
        *(f32x2*)&Tloc[(((size_t)b * N_DIM + jbase + j) * C_DIM + c) * 2] =
            (f32x2){se, sg};
    }
    *(f32x2*)&tot[(((size_t)b * 64 + tile) * C_DIM + c) * 2] = (f32x2){se, sg};
}

// exclusive scan of 64 tile totals per (b,c) + grand total in slot 64
__global__ __launch_bounds__(320) void k_scan(const float* __restrict__ tot,
                                              float* __restrict__ off) {
    const int b = blockIdx.x, c = threadIdx.x;
    float ae = 0.f, ag = 0.f;
    #pragma unroll 8
    for (int t = 0; t < 64; ++t) {
        *(f32x2*)&off[(((size_t)b * 65 + t) * C_DIM + c) * 2] = (f32x2){ae, ag};
        f32x2 v = *(const f32x2*)&tot[(((size_t)b * 64 + t) * C_DIM + c) * 2];
        ae += v[0]; ag += v[1];
    }
    *(f32x2*)&off[(((size_t)b * 65 + 64) * C_DIM + c) * 2] = (f32x2){ae, ag};
}

// lookup (batched gathers) + transpose + residual
__global__ __launch_bounds__(256) void k_out(const float* __restrict__ x,
                                             const float* __restrict__ Tloc,
                                             const float* __restrict__ off,
                                             const int* __restrict__ JnA,
                                             const float* __restrict__ fzA,
                                             const float* __restrict__ hzA,
                                             float* __restrict__ out) {
    __shared__ float tile[64][65];
    const int b = blockIdx.z, cg = blockIdx.y, n0 = blockIdx.x * 64;
    const int tid = threadIdx.x, w = tid >> 6, l = tid & 63;
    const int c0 = cg * 64;

    const f32x2 gt = *(const f32x2*)&off[(((size_t)b * 65 + 64) * C_DIM + c0 + l) * 2];

    f32x2 tv[16], ov[16];
    float fzs[16], hzs[16], msk[16];
    #pragma unroll
    for (int i = 0; i < 16; ++i) {
        const int n = n0 + w * 16 + i;
        const int Jn = JnA[b * N_DIM + n];
        fzs[i] = fzA[b * N_DIM + n];
        hzs[i] = hzA[b * N_DIM + n];
        const int jt = Jn >> 6, jl = Jn & 63;
        msk[i] = jl ? 1.f : 0.f;
        const int jrow = jl ? (Jn - 1) : 0;
        ov[i] = *(const f32x2*)&off[(((size_t)b * 65 + jt) * C_DIM + c0 + l) * 2];
        tv[i] = *(const f32x2*)&Tloc[(((size_t)b * N_DIM + jrow) * C_DIM + c0 + l) * 2];
    }
    #pragma unroll
    for (int i = 0; i < 16; ++i) {
        const float se_ex = ov[i][0] + msk[i] * tv[i][0];
        const float sg_ex = ov[i][1] + msk[i] * tv[i][1];
        tile[l][w * 16 + i] = fzs[i] * (gt[0] - se_ex) + hzs[i] * sg_ex;
    }
    __syncthreads();
    const int row = tid >> 2, nseg = (tid & 3) * 16;
    const size_t gidx = ((size_t)(b * C_DIM + c0 + row)) * N_DIM + n0 + nseg;
    #pragma unroll
    for (int i2 = 0; i2 < 16; i2 += 4) {
        f32x4 xv = *(const f32x4*)&x[gidx + i2];
        f32x4 o;
        #pragma unroll
        for (int q = 0; q < 4; ++q) o[q] = tile[row][nseg + i2 + q] + xv[q];
        *(f32x4*)&out[gidx + i2] = o;
    }
}

// ============================================================
// MID fallback: round-3 path (proven 75 us)
// ============================================================

__global__ __launch_bounds__(256) void k_s12(const float* __restrict__ x,
                                             const float* __restrict__ W,
                                             float* __restrict__ s1p,
                                             float* __restrict__ s2p,
                                             short* __restrict__ xb) {
    const int b = blockIdx.z, cb = blockIdx.y;
    const int nl = threadIdx.x & 63, cw = threadIdx.x >> 6;
    const int n = blockIdx.x * 64 + nl;
    const int cbase = cb * 64 + cw * 16;
    const float* px = x + ((size_t)b * C_DIM + cbase) * N_DIM + n;
    short* pxb = xb + ((size_t)b * C_DIM + cbase) * N_DIM + n;
    const float* w1 = W + cbase;
    const float* w2 = W + C_DIM + cbase;
    float a1 = 0.f, a2 = 0.f;
    #pragma unroll
    for (int cc = 0; cc < 16; ++cc) {
        float v = px[(size_t)cc * N_DIM];
        a1 = fmaf(v, w1[cc], a1);
        a2 = fmaf(v, w2[cc], a2);
        __hip_bfloat16 hv = __float2bfloat16(v);
        pxb[(size_t)cc * N_DIM] = *(short*)&hv;
    }
    __shared__ float r1[4][64], r2[4][64];
    r1[cw][nl] = a1; r2[cw][nl] = a2;
    __syncthreads();
    if (threadIdx.x < 64) {
        s1p[((size_t)b * 5 + cb) * N_DIM + n] = r1[0][nl] + r1[1][nl] + r1[2][nl] + r1[3][nl];
        s2p[((size_t)b * 5 + cb) * N_DIM + n] = r2[0][nl] + r2[1][nl] + r2[2][nl] + r2[3][nl];
    }
}

__global__ __launch_bounds__(1024) void k_fold(const float* __restrict__ s1p,
                                               const float* __restrict__ s2p,
                                               float* __restrict__ s2,
                                               float* __restrict__ Ekf,
                                               float* __restrict__ Gkf,
                                               float* __restrict__ s1max) {
    const int b = blockIdx.x, tid = threadIdx.x;
    __shared__ float md[1024];
    float mx = -3.4e38f;
    for (int n = tid; n < N_DIM; n += 1024) {
        float v1 = 0.f, v2 = 0.f;
        #pragma unroll
        for (int cb = 0; cb < 5; ++cb) {
            v1 += s1p[((size_t)b * 5 + cb) * N_DIM + n];
            v2 += s2p[((size_t)b * 5 + cb) * N_DIM + n];
        }
        s2[b * N_DIM + n] = v2;
        Ekf[b * N_DIM + n] = __expf(v1);
        Gkf[b * N_DIM + n] = __expf(NEG * v1);
        mx = fmaxf(mx, v1);
    }
    md[tid] = mx;
    __syncthreads();
    for (int s = 512; s > 0; s >>= 1) {
        if (tid < s) md[tid] = fmaxf(md[tid], md[tid + s]);
        __syncthreads();
    }
    if (tid == 0) s1max[b] = md[0];
}

__global__ __launch_bounds__(256) void k_z(const float* __restrict__ s2,
                                           const float* __restrict__ s1max,
                                           const float* __restrict__ Ekf,
                                           const float* __restrict__ Gkf,
                                           float* __restrict__ Fz,
                                           float* __restrict__ Hz) {
    __shared__ __align__(16) float Els[4096], Gls[4096];
    const int b = blockIdx.y, tid = threadIdx.x;
    const int w = tid >> 6, l = tid & 63;
    const float* Eb = Ekf + b * N_DIM;
    const float* Gb = Gkf + b * N_DIM;
    #pragma unroll
    for (int i = 0; i < 4; ++i) {
        int chn = i * 256 + tid;
        *(f32x4*)&Els[chn * 4] = *(const f32x4*)&Eb[chn * 4];
        *(f32x4*)&Gls[chn * 4] = *(const f32x4*)&Gb[chn * 4];
    }
    __syncthreads();
    float smax = s1max[b];
    #pragma unroll
    for (int rr = 0; rr < 4; ++rr) {
        int row = b * N_DIM + blockIdx.x * 16 + w * 4 + rr;
        float s2n = s2[row];
        float mn = lrelu(s2n + smax);
        float F = __expf(s2n - mn), H = __expf(NEG * s2n - mn);
        float sum = 0.f;
        #pragma unroll 4
        for (int i = 0; i < 16; ++i) {
            int k = i * 256 + l * 4;
            f32x4 e = *(const f32x4*)&Els[k];
            f32x4 gg = *(const f32x4*)&Gls[k];
            #pragma unroll
            for (int j = 0; j < 4; ++j) sum += fmaxf(e[j] * F, gg[j] * H);
        }
        #pragma unroll
        for (int off = 32; off > 0; off >>= 1) sum += __shfl_down(sum, off);
        if (l == 0) {
            float rz = 1.f / sum;
            Fz[row] = F * rz;
            Hz[row] = H * rz;
        }
    }
}

__global__ __launch_bounds__(128) void k_gemm(const short* __restrict__ xb,
                                              const float* __restrict__ x,
                                              const float* __restrict__ Ekf,
                                              const float* __restrict__ Gkf,
                                              const float* __restrict__ Fz,
                                              const float* __restrict__ Hz,
                                              float* __restrict__ out) {
    __shared__ __align__(16) short Asm[2][2][4096];
    __shared__ __align__(16) float EGs[2][2][256];

    const int b = blockIdx.z, c0 = blockIdx.y * 64, n0 = blockIdx.x * 64;
    const int tid = threadIdx.x;
    const int h = tid >> 6, l = tid & 63, lr = l & 15, g = l >> 4;
    const short* xbp = xb + (size_t)b * C_DIM * N_DIM + h * 2048;
    const float* Eb = Ekf + b * N_DIM + h * 2048;
    const float* Gb = Gkf + b * N_DIM + h * 2048;

    int ncol[4]; float fz[4], hz[4];
    #pragma unroll
    for (int t = 0; t < 4; ++t) {
        int n = n0 + t * 16 + lr;
        ncol[t] = n;
        fz[t] = Fz[b * N_DIM + n];
        hz[t] = Hz[b * N_DIM + n];
    }

    f32x4 acc[4][4];
    #pragma unroll
    for (int i = 0; i < 4; ++i)
        #pragma unroll
        for (int t = 0; t < 4; ++t) acc[i][t] = (f32x4){0.f, 0.f, 0.f, 0.f};

    auto stageA = [&](int buf, int it) {
        #pragma unroll
        for (int i = 0; i < 8; ++i) {
            int row = i * 8 + (l >> 3);
            int c8 = (l & 7) ^ (row & 7);
            gload_lds16(xbp + (size_t)(c0 + row) * N_DIM + it * 64 + c8 * 8,
                        &Asm[h][buf][i * 512]);
        }
    };
    auto stageEG = [&](int buf, int it) {
        int lm = l & 31;
        const float* p = (lm < 16) ? (Eb + it * 64 + lm * 4)
                                   : (Gb + it * 64 + (lm - 16) * 4);
        gload_lds16(p, &EGs[h][buf][0]);
    };

    stageA(0, 0); stageEG(0, 0);
    for (int it = 0; it < 32; ++it) {
        const int buf = it & 1;
        if (it < 31) {
            stageA(buf ^ 1, it + 1);
            stageEG(buf ^ 1, it + 1);
            asm volatile("s_waitcnt vmcnt(9)" ::: "memory");
        } else {
            asm volatile("s_waitcnt vmcnt(0)" ::: "memory");
        }
        __builtin_amdgcn_sched_barrier(0);
        #pragma unroll
        for (int s = 0; s < 2; ++s) {
            const int kk = s * 32 + g * 8;
            f32x4 e0 = *(const f32x4*)&EGs[h][buf][kk];
            f32x4 e1 = *(const f32x4*)&EGs[h][buf][kk + 4];
            f32x4 g0 = *(const f32x4*)&EGs[h][buf][64 + kk];
            f32x4 g1 = *(const f32x4*)&EGs[h][buf][64 + kk + 4];
            bf16x8 afr[4];
            #pragma unroll
            for (int i = 0; i < 4; ++i) {
                int row = 16 * i + lr;
                int idx = row * 64 + (((4 * s + g) ^ (row & 7)) * 8);
                afr[i] = *(const bf16x8*)&Asm[h][buf][idx];
            }
            bf16x8 bfr[4];
            #pragma unroll
            for (int t = 0; t < 4; ++t) {
                bfv8 qv;
                #pragma unroll
                for (int j = 0; j < 4; ++j) {
                    qv[j]     = (__bf16)fmaxf(e0[j] * fz[t], g0[j] * hz[t]);
                    qv[j + 4] = (__bf16)fmaxf(e1[j] * fz[t], g1[j] * hz[t]);
                }
                bfr[t] = __builtin_bit_cast(bf16x8, qv);
            }
            #pragma unroll
            for (int i = 0; i < 4; ++i)
                #pragma unroll
                for (int t = 0; t < 4; ++t)
                    acc[i][t] = __builtin_amdgcn_mfma_f32_16x16x32_bf16(
                        afr[i], bfr[t], acc[i][t], 0, 0, 0);
        }
    }

    __syncthreads();
    float* red = (float*)&Asm[0][0][0];
    if (h == 1) {
        #pragma unroll
        for (int i = 0; i < 4; ++i)
            #pragma unroll
            for (int t = 0; t < 4; ++t)
                #pragma unroll
                for (int r = 0; r < 4; ++r)
                    red[((i * 4 + t) * 4 + r) * 64 + l] = acc[i][t][r];
    }
    __syncthreads();
    if (h == 0) {
        #pragma unroll
        for (int i = 0; i < 4; ++i)
            #pragma unroll
            for (int t = 0; t < 4; ++t)
                #pragma unroll
                for (int r = 0; r < 4; ++r) {
                    float v = acc[i][t][r] + red[((i * 4 + t) * 4 + r) * 64 + l];
                    int c = c0 + 16 * i + g * 4 + r;
                    size_t idx = ((size_t)(b * C_DIM + c)) * N_DIM + ncol[t];
                    out[idx] = v + x[idx];
                }
    }
}

// ============================================================
// LAST fallback: round-1 path (proven)
// ============================================================

__global__ __launch_bounds__(256) void k_s12_fb(const float* __restrict__ x,
                                                const float* __restrict__ W,
                                                float* __restrict__ s1,
                                                float* __restrict__ s2) {
    int b = blockIdx.y;
    int n = blockIdx.x * 256 + threadIdx.x;
    const float* px = x + ((size_t)b * C_DIM) * N_DIM + n;
    float a1 = 0.f, a2 = 0.f;
    #pragma unroll 4
    for (int c = 0; c < C_DIM; ++c) {
        float v = px[(size_t)c * N_DIM];
        a1 = fmaf(v, W[c], a1);
        a2 = fmaf(v, W[C_DIM + c], a2);
    }
    s1[b * N_DIM + n] = a1;
    s2[b * N_DIM + n] = a2;
}

__global__ __launch_bounds__(256) void k_max_fb(const float* __restrict__ s1,
                                                float* __restrict__ s1max) {
    __shared__ float red[256];
    int b = blockIdx.x, tid = threadIdx.x;
    float mx = -3.4e38f;
    for (int k = tid; k < N_DIM; k += 256) mx = fmaxf(mx, s1[b * N_DIM + k]);
    red[tid] = mx;
    __syncthreads();
    for (int s = 128; s > 0; s >>= 1) {
        if (tid < s) red[tid] = fmaxf(red[tid], red[tid + s]);
        __syncthreads();
    }
    if (tid == 0) s1max[b] = red[0];
}

__global__ __launch_bounds__(256) void k_z_fb(const float* __restrict__ s1,
                                              const float* __restrict__ s2,
                                              const float* __restrict__ s1max,
                                              float* __restrict__ mArr,
                                              float* __restrict__ rZ) {
    int w = threadIdx.x >> 6, l = threadIdx.x & 63;
    int row = blockIdx.x * 4 + w;
    int b = row >> 12;
    const float* s1b = s1 + b * N_DIM;
    float s2n = s2[row];
    float mn = lrelu(s2n + s1max[b]);
    float sum = 0.f;
    for (int k = l; k < N_DIM; k += 64)
        sum += __expf(lrelu(s2n + s1b[k]) - mn);
    #pragma unroll
    for (int off = 32; off > 0; off >>= 1) sum += __shfl_down(sum, off);
    if (l == 0) { mArr[row] = mn; rZ[row] = 1.f / sum; }
}

__global__ __launch_bounds__(256) void k_gemm_fb(const float* __restrict__ x,
                                                 const float* __restrict__ s1,
                                                 const float* __restrict__ s2,
                                                 const float* __restrict__ mArr,
                                                 const float* __restrict__ rZ,
                                                 float* __restrict__ out) {
    const int b = blockIdx.z, c0 = blockIdx.y * 64, n0 = blockIdx.x * 128;
    const int tid = threadIdx.x;
    const int w = tid >> 6, l = tid & 63, lr = l & 15, g = l >> 4;
    const float* pb = x + (size_t)b * C_DIM * N_DIM;
    const float* s1b = s1 + b * N_DIM;
    int ncol[2]; float s2c[2], mc[2], rzc[2];
    #pragma unroll
    for (int t = 0; t < 2; ++t) {
        int n = n0 + w * 32 + t * 16 + lr;
        ncol[t] = n; s2c[t] = s2[b * N_DIM + n];
        mc[t] = mArr[b * N_DIM + n]; rzc[t] = rZ[b * N_DIM + n];
    }
    f32x4 acc[4][2];
    #pragma unroll
    for (int i = 0; i < 4; ++i)
        #pragma unroll
        for (int t = 0; t < 2; ++t) acc[i][t] = (f32x4){0.f, 0.f, 0.f, 0.f};
    for (int k0 = 0; k0 < N_DIM; k0 += 32) {
        const int kk = k0 + g * 8;
        f32x4 s1lo = *(const f32x4*)(s1b + kk);
        f32x4 s1hi = *(const f32x4*)(s1b + kk + 4);
        bf16x8 afrag[4];
        #pragma unroll
        for (int i = 0; i < 4; ++i) {
            const float* ap = pb + (size_t)(c0 + i * 16 + lr) * N_DIM + kk;
            f32x4 lo = *(const f32x4*)ap;
            f32x4 hi = *(const f32x4*)(ap + 4);
            bfv8 av;
            #pragma unroll
            for (int j = 0; j < 4; ++j) { av[j] = (__bf16)lo[j]; av[j + 4] = (__bf16)hi[j]; }
            afrag[i] = __builtin_bit_cast(bf16x8, av);
        }
        bf16x8 bfrag[2];
        #pragma unroll
        for (int t = 0; t < 2; ++t) {
            bfv8 qv;
            #pragma unroll
            for (int j = 0; j < 8; ++j) {
                float s1k = (j < 4) ? s1lo[j] : s1hi[j - 4];
                float q = __expf(lrelu(s2c[t] + s1k) - mc[t]) * rzc[t];
                qv[j] = (__bf16)q;
            }
            bfrag[t] = __builtin_bit_cast(bf16x8, qv);
        }
        #pragma unroll
        for (int i = 0; i < 4; ++i)
            #pragma unroll
            for (int t = 0; t < 2; ++t)
                acc[i][t] = __builtin_amdgcn_mfma_f32_16x16x32_bf16(
                    afrag[i], bfrag[t], acc[i][t], 0, 0, 0);
    }
    #pragma unroll
    for (int i = 0; i < 4; ++i)
        #pragma unroll
        for (int t = 0; t < 2; ++t)
            #pragma unroll
            for (int r = 0; r < 4; ++r) {
                int c = c0 + i * 16 + g * 4 + r;
                size_t idx = ((size_t)(b * C_DIM + c)) * N_DIM + ncol[t];
                out[idx] = acc[i][t][r] + x[idx];
            }
}

// ============================================================
// launch
// ============================================================

extern "C" void kernel_launch(void* const* d_in, const int* in_sizes, int n_in,
                              void* d_out, int out_size, void* d_ws, size_t ws_size,
                              hipStream_t stream) {
    const float* x = (const float*)d_in[0];
    const float* W = (const float*)d_in[1];
    float* out = (float*)d_out;
    float* ws = (float*)d_ws;

    // ---- new-path ws layout (float offsets) ----
    const size_t o_s1 = 0, o_s2 = 8192, o_S = 16384, o_idx = 24576,
                 o_EP = 32768, o_GP = 40968, o_Eg = 49168, o_Gg = 57360,
                 o_Jn = 65552, o_fz = 73744, o_hz = 81936, o_pc = 90128,
                 o_tot = 155664, o_off = 237584, o_xT = 320784,
                 o_Tl = 2942224, o_end = 8185104;
    const size_t need_new = o_end * 4;

    // ---- mid-path (round-3) ws layout ----
    const size_t m_s1p = 0, m_s2p = 40960, m_s2 = 81920, m_Ek = 90112,
                 m_Gk = 98304, m_Fz = 106496, m_Hz = 114688, m_mx = 122880,
                 m_xb = 122888;
    const size_t need_mid = m_xb * 4 + (size_t)2 * C_DIM * N_DIM * 2;

    if (ws_size >= need_new) {
        float* s1 = ws + o_s1;
        float* s2 = ws + o_s2;
        float* Sg = ws + o_S;
        int*   idxg = (int*)(ws + o_idx);
        float* EP = ws + o_EP;
        float* GP = ws + o_GP;
        float* Eg = ws + o_Eg;
        float* Gg = ws + o_Gg;
        int*   JnA = (int*)(ws + o_Jn);
        float* fzA = ws + o_fz;
        float* hzA = ws + o_hz;
        int*   pcnt = (int*)(ws + o_pc);
        float* tot = ws + o_tot;
        float* off = ws + o_off;
        float* xT = ws + o_xT;
        float* Tloc = ws + o_Tl;

        k_pre   <<<dim3(64, 2), 256, 0, stream>>>(x, W, s1, s2, xT);
        k_rank  <<<dim3(8, 16, 2), 256, 0, stream>>>(s1, pcnt);
        k_sct   <<<2, 1024, 0, stream>>>(s1, pcnt, Sg, idxg, EP, GP, Eg, Gg);
        k_jz    <<<dim3(16, 2), 256, 0, stream>>>(s2, Sg, EP, GP, JnA, fzA, hzA);
        k_prefix<<<dim3(16, 5, 2), 256, 0, stream>>>(xT, idxg, Eg, Gg, Tloc, tot);
        k_scan  <<<2, 320, 0, stream>>>(tot, off);
        k_out   <<<dim3(64, 5, 2), 256, 0, stream>>>(x, Tloc, off, JnA, fzA, hzA, out);
    } else if (ws_size >= need_mid) {
        float* s1p = ws + m_s1p;
        float* s2p = ws + m_s2p;
        float* s2  = ws + m_s2;
        float* Ekf = ws + m_Ek;
        float* Gkf = ws + m_Gk;
        float* Fz  = ws + m_Fz;
        float* Hz  = ws + m_Hz;
        float* s1max = ws + m_mx;
        short* xb = (short*)(ws + m_xb);
        k_s12 <<<dim3(64, 5, 2), 256, 0, stream>>>(x, W, s1p, s2p, xb);
        k_fold<<<2, 1024, 0, stream>>>(s1p, s2p, s2, Ekf, Gkf, s1max);
        k_z   <<<dim3(256, 2), 256, 0, stream>>>(s2, s1max, Ekf, Gkf, Fz, Hz);
        k_gemm<<<dim3(64, 5, 2), 128, 0, stream>>>(xb, x, Ekf, Gkf, Fz, Hz, out);
    } else {
        float* s1 = ws;
        float* s2 = ws + 8192;
        float* mArr = ws + 16384;
        float* rZ = ws + 24576;
        float* s1max = ws + 32768;
        k_s12_fb<<<dim3(N_DIM / 256, 2), 256, 0, stream>>>(x, W, s1, s2);
        k_max_fb<<<2, 256, 0, stream>>>(s1, s1max);
        k_z_fb<<<(2 * N_DIM) / 4, 256, 0, stream>>>(s1, s2, s1max, mArr, rZ);
        k_gemm_fb<<<dim3(N_DIM / 128, C_DIM / 64, 2), 256, 0, stream>>>(x, s1, s2, mArr, rZ, out);
    }
}

// Round 7
// 59.585 us; speedup vs baseline: 1.5456x; 1.0776x over previous
//
#include <hip/hip_runtime.h>
#include <hip/hip_bf16.h>

#define C_DIM 320
#define N_DIM 4096
#define NEG 0.01f

typedef float f32x4 __attribute__((ext_vector_type(4)));
typedef float f32x2 __attribute__((ext_vector_type(2)));
typedef short bf16x8 __attribute__((ext_vector_type(8)));
typedef __bf16 bfv8 __attribute__((ext_vector_type(8)));

__device__ __forceinline__ float lrelu(float e) { return fmaxf(e, NEG * e); }

__device__ __forceinline__ unsigned short bf16bits(float v) {
    __hip_bfloat16 h = __float2bfloat16(v);
    return *(unsigned short*)&h;
}
__device__ __forceinline__ float bf16tof(unsigned short u) {
    unsigned int bits = ((unsigned int)u) << 16;
    return __builtin_bit_cast(float, bits);
}

__device__ __forceinline__ void gload_lds16(const void* g, void* l) {
    __builtin_amdgcn_global_load_lds(
        (const __attribute__((address_space(1))) void*)g,
        (__attribute__((address_space(3))) void*)l, 16, 0, 0);
}

// ============================================================
// Sorted-prefix algorithm (no GEMM):
// out[c,n] = fz[n]*(SEtot[c] - SE_ex(Jn)[c]) + hz[n]*SG_ex(Jn)[c] + P[c,n]
// k sorted ascending by s1; Jn = lower_bound(S, -s2[n]).
// 5 dispatches: pre -> rank -> sct(+jz) -> prefix -> out(+scan)
// ============================================================

// s1/s2 dot products + transposed bf16 copy xT[b][n][c]
__global__ __launch_bounds__(256) void k_pre(const float* __restrict__ x,
                                             const float* __restrict__ W,
                                             float* __restrict__ s1,
                                             float* __restrict__ s2,
                                             short* __restrict__ xT) {
    __shared__ float tile[64][65];
    __shared__ float r1[4][64], r2[4][64];
    const int b = blockIdx.y;
    const int nl = threadIdx.x & 63, cw = threadIdx.x >> 6;
    const int n0 = blockIdx.x * 64;
    const int n = n0 + nl;
    float a1 = 0.f, a2 = 0.f;
    for (int sub = 0; sub < 5; ++sub) {
        const int cb = sub * 64 + cw * 16;
        #pragma unroll
        for (int cc = 0; cc < 16; ++cc) {
            const int c = cb + cc;
            float v = x[((size_t)(b * C_DIM + c)) * N_DIM + n];
            a1 = fmaf(v, W[c], a1);
            a2 = fmaf(v, W[C_DIM + c], a2);
            tile[cw * 16 + cc][nl] = v;
        }
        __syncthreads();
        #pragma unroll
        for (int rr = 0; rr < 16; ++rr) {
            const int nloc = cw * 16 + rr;
            xT[((size_t)b * N_DIM + n0 + nloc) * C_DIM + sub * 64 + nl] =
                (short)bf16bits(tile[nl][nloc]);
        }
        __syncthreads();
    }
    r1[cw][nl] = a1; r2[cw][nl] = a2;
    __syncthreads();
    if (threadIdx.x < 64) {
        s1[b * N_DIM + n] = r1[0][nl] + r1[1][nl] + r1[2][nl] + r1[3][nl];
        s2[b * N_DIM + n] = r2[0][nl] + r2[1][nl] + r2[2][nl] + r2[3][nl];
    }
}

// partial ranks: pcnt[b][chunk][k] = #{k' in chunk: s1[k'] < s1[k] (tie: k'<k)}
__global__ __launch_bounds__(256) void k_rank(const float* __restrict__ s1,
                                              int* __restrict__ pcnt) {
    __shared__ float ch[512];
    const int chunk = blockIdx.x, kt = blockIdx.y, b = blockIdx.z;
    const int tid = threadIdx.x;
    const int kbase = chunk * 512;
    ch[tid] = s1[b * N_DIM + kbase + tid];
    ch[tid + 256] = s1[b * N_DIM + kbase + tid + 256];
    __syncthreads();
    const int k = kt * 256 + tid;
    const float v = s1[b * N_DIM + k];
    int cnt = 0;
    #pragma unroll 8
    for (int i = 0; i < 512; ++i) {
        float sv = ch[i];
        int kc = kbase + i;
        cnt += (sv < v || (sv == v && kc < k)) ? 1 : 0;
    }
    pcnt[(b * 8 + chunk) * N_DIM + k] = cnt;
}

// scatter into sorted order + EP/GP scans (kept in LDS) + sorted Eg/Gg
// + fused jz: Jn/fz/hz per n (binary search over LDS-resident sorted S)
__global__ __launch_bounds__(1024) void k_sct(const float* __restrict__ s1,
                                              const float* __restrict__ s2,
                                              const int* __restrict__ pcnt,
                                              float* __restrict__ Sg,
                                              int* __restrict__ idxg,
                                              float* __restrict__ Eg,
                                              float* __restrict__ Gg,
                                              int* __restrict__ JnA,
                                              float* __restrict__ fzA,
                                              float* __restrict__ hzA) {
    __shared__ float sv[4096];
    __shared__ int si[4096];
    __shared__ float ep[4097], gp[4097];
    __shared__ float wte[16], wtg[16];
    const int b = blockIdx.x, tid = threadIdx.x;
    #pragma unroll
    for (int q = 0; q < 4; ++q) {
        const int k = q * 1024 + tid;
        int r = 0;
        #pragma unroll
        for (int c = 0; c < 8; ++c) r += pcnt[(b * 8 + c) * N_DIM + k];
        sv[r] = s1[b * N_DIM + k];
        si[r] = k;
    }
    __syncthreads();
    const int j0 = tid * 4;
    float pe[4], pg[4];
    {
        float v0 = sv[j0], v1 = sv[j0 + 1], v2 = sv[j0 + 2], v3 = sv[j0 + 3];
        float e0 = __expf(v0), e1 = __expf(v1), e2 = __expf(v2), e3 = __expf(v3);
        float g0 = __expf(NEG * v0), g1 = __expf(NEG * v1);
        float g2 = __expf(NEG * v2), g3 = __expf(NEG * v3);
        Eg[b * N_DIM + j0] = e0; Eg[b * N_DIM + j0 + 1] = e1;
        Eg[b * N_DIM + j0 + 2] = e2; Eg[b * N_DIM + j0 + 3] = e3;
        Gg[b * N_DIM + j0] = g0; Gg[b * N_DIM + j0 + 1] = g1;
        Gg[b * N_DIM + j0 + 2] = g2; Gg[b * N_DIM + j0 + 3] = g3;
        pe[0] = e0; pe[1] = pe[0] + e1; pe[2] = pe[1] + e2; pe[3] = pe[2] + e3;
        pg[0] = g0; pg[1] = pg[0] + g1; pg[2] = pg[1] + g2; pg[3] = pg[2] + g3;
    }
    const float te = pe[3], tg = pg[3];
    const int lane = tid & 63, wid = tid >> 6;
    float ie = te, ig = tg;
    #pragma unroll
    for (int o = 1; o < 64; o <<= 1) {
        float ue = __shfl_up(ie, o);
        float ug = __shfl_up(ig, o);
        if (lane >= o) { ie += ue; ig += ug; }
    }
    if (lane == 63) { wte[wid] = ie; wtg[wid] = ig; }
    __syncthreads();
    float oe = 0.f, og = 0.f;
    for (int wq = 0; wq < wid; ++wq) { oe += wte[wq]; og += wtg[wq]; }
    const float be = oe + ie - te, bg = og + ig - tg;
    #pragma unroll
    for (int i = 0; i < 4; ++i) {
        ep[j0 + i] = be + (i ? pe[i - 1] : 0.f);
        gp[j0 + i] = bg + (i ? pg[i - 1] : 0.f);
    }
    if (tid == 1023) {
        ep[4096] = oe + ie;
        gp[4096] = og + ig;
    }
    #pragma unroll
    for (int q = 0; q < 4; ++q) {
        const int j = q * 1024 + tid;
        Sg[b * N_DIM + j] = sv[j];
        idxg[b * N_DIM + j] = si[j];
    }
    __syncthreads();
    // jz phase: sorted S + scans are LDS-resident
    const float smax = sv[4095];
    const float EPt = ep[4096];
    #pragma unroll
    for (int q = 0; q < 4; ++q) {
        const int n = q * 1024 + tid;
        const float s2n = s2[b * N_DIM + n];
        const float mn = lrelu(s2n + smax);
        const float F = __expf(s2n - mn), H = __expf(NEG * s2n - mn);
        const float t = -s2n;
        int lo = 0, hi = 4096;
        while (lo < hi) {
            int mid = (lo + hi) >> 1;
            if (sv[mid] < t) lo = mid + 1; else hi = mid;
        }
        const float suf = EPt - ep[lo];
        const float pre = gp[lo];
        const float rz = 1.f / (F * suf + H * pre);
        JnA[b * N_DIM + n] = lo;
        fzA[b * N_DIM + n] = F * rz;
        hzA[b * N_DIM + n] = H * rz;
    }
}

// per (b, cg, 64-j tile): wave-local inclusive prefixes of P*e^{S}, P*e^{.01S}
// xT bf16 reads; Tloc packed 2xbf16; tot fp32
__global__ __launch_bounds__(256) void k_prefix(const short* __restrict__ xT,
                                                const int* __restrict__ idxg,
                                                const float* __restrict__ Eg,
                                                const float* __restrict__ Gg,
                                                unsigned int* __restrict__ Tloc,
                                                float* __restrict__ tot) {
    const int jt4 = blockIdx.x, cg = blockIdx.y, b = blockIdx.z;
    const int w = threadIdx.x >> 6, l = threadIdx.x & 63;
    const int tile = jt4 * 4 + w;
    const int jbase = tile * 64;
    const int c = cg * 64 + l;
    const short* xTb = xT + (size_t)b * N_DIM * C_DIM;
    const float ej = Eg[b * N_DIM + jbase + l];
    const float gj = Gg[b * N_DIM + jbase + l];
    const int   ij = idxg[b * N_DIM + jbase + l];
    float se = 0.f, sg = 0.f;
    #pragma unroll 16
    for (int j = 0; j < 64; ++j) {
        const float e = __shfl(ej, j);
        const float g = __shfl(gj, j);
        const int kidx = __shfl(ij, j);
        const float xv = bf16tof((unsigned short)xTb[(size_t)kidx * C_DIM + c]);
        se = fmaf(xv, e, se);
        sg = fmaf(xv, g, sg);
        Tloc[((size_t)b * N_DIM + jbase + j) * C_DIM + c] =
            (unsigned int)bf16bits(se) | ((unsigned int)bf16bits(sg) << 16);
    }
    *(f32x2*)&tot[(((size_t)b * 64 + tile) * C_DIM + c) * 2] = (f32x2){se, sg};
}

// fused: per-block tile-offset scan (from fp32 tot) + lookup + transpose + residual
__global__ __launch_bounds__(256) void k_out(const float* __restrict__ x,
                                             const unsigned int* __restrict__ Tloc,
                                             const float* __restrict__ tot,
                                             const int* __restrict__ JnA,
                                             const float* __restrict__ fzA,
                                             const float* __restrict__ hzA,
                                             float* __restrict__ out) {
    __shared__ float offl[65][64][2];
    __shared__ float wsum[4][64][2];
    __shared__ float tile[64][65];
    const int b = blockIdx.z, cg = blockIdx.y, n0 = blockIdx.x * 64;
    const int tid = threadIdx.x, w = tid >> 6, l = tid & 63;
    const int c0 = cg * 64;

    // 2-level scan of 64 tile totals: wave w owns jt in [16w, 16w+16)
    float ae = 0.f, ag = 0.f;
    #pragma unroll
    for (int i = 0; i < 16; ++i) {
        const int jt = w * 16 + i;
        offl[jt][l][0] = ae; offl[jt][l][1] = ag;
        f32x2 v = *(const f32x2*)&tot[(((size_t)b * 64 + jt) * C_DIM + c0 + l) * 2];
        ae += v[0]; ag += v[1];
    }
    wsum[w][l][0] = ae; wsum[w][l][1] = ag;
    __syncthreads();
    float be = 0.f, bg = 0.f;
    for (int ww = 0; ww < w; ++ww) { be += wsum[ww][l][0]; bg += wsum[ww][l][1]; }
    #pragma unroll
    for (int i = 0; i < 16; ++i) {
        const int jt = w * 16 + i;
        offl[jt][l][0] += be; offl[jt][l][1] += bg;
    }
    if (w == 3) { offl[64][l][0] = be + ae; offl[64][l][1] = bg + ag; }
    __syncthreads();

    const float gtE = offl[64][l][0];

    unsigned int tvp[16];
    f32x2 ov[16];
    float fzs[16], hzs[16], msk[16];
    #pragma unroll
    for (int i = 0; i < 16; ++i) {
        const int n = n0 + w * 16 + i;
        const int Jn = JnA[b * N_DIM + n];
        fzs[i] = fzA[b * N_DIM + n];
        hzs[i] = hzA[b * N_DIM + n];
        const int jt = Jn >> 6, jl = Jn & 63;
        msk[i] = jl ? 1.f : 0.f;
        const int jrow = jl ? (Jn - 1) : 0;
        ov[i][0] = offl[jt][l][0];
        ov[i][1] = offl[jt][l][1];
        tvp[i] = Tloc[((size_t)b * N_DIM + jrow) * C_DIM + c0 + l];
    }
    #pragma unroll
    for (int i = 0; i < 16; ++i) {
        const float tvE = bf16tof((unsigned short)(tvp[i] & 0xFFFFu));
        const float tvG = bf16tof((unsigned short)(tvp[i] >> 16));
        const float se_ex = ov[i][0] + msk[i] * tvE;
        const float sg_ex = ov[i][1] + msk[i] * tvG;
        tile[l][w * 16 + i] = fzs[i] * (gtE - se_ex) + hzs[i] * sg_ex;
    }
    __syncthreads();
    const int row = tid >> 2, nseg = (tid & 3) * 16;
    const size_t gidx = ((size_t)(b * C_DIM + c0 + row)) * N_DIM + n0 + nseg;
    #pragma unroll
    for (int i2 = 0; i2 < 16; i2 += 4) {
        f32x4 xv = *(const f32x4*)&x[gidx + i2];
        f32x4 o;
        #pragma unroll
        for (int q = 0; q < 4; ++q) o[q] = tile[row][nseg + i2 + q] + xv[q];
        *(f32x4*)&out[gidx + i2] = o;
    }
}

// ============================================================
// MID fallback: round-3 path (proven 75 us)
// ============================================================

__global__ __launch_bounds__(256) void k_s12(const float* __restrict__ x,
                                             const float* __restrict__ W,
                                             float* __restrict__ s1p,
                                             float* __restrict__ s2p,
                                             short* __restrict__ xb) {
    const int b = blockIdx.z, cb = blockIdx.y;
    const int nl = threadIdx.x & 63, cw = threadIdx.x >> 6;
    const int n = blockIdx.x * 64 + nl;
    const int cbase = cb * 64 + cw * 16;
    const float* px = x + ((size_t)b * C_DIM + cbase) * N_DIM + n;
    short* pxb = xb + ((size_t)b * C_DIM + cbase) * N_DIM + n;
    const float* w1 = W + cbase;
    const float* w2 = W + C_DIM + cbase;
    float a1 = 0.f, a2 = 0.f;
    #pragma unroll
    for (int cc = 0; cc < 16; ++cc) {
        float v = px[(size_t)cc * N_DIM];
        a1 = fmaf(v, w1[cc], a1);
        a2 = fmaf(v, w2[cc], a2);
        __hip_bfloat16 hv = __float2bfloat16(v);
        pxb[(size_t)cc * N_DIM] = *(short*)&hv;
    }
    __shared__ float r1[4][64], r2[4][64];
    r1[cw][nl] = a1; r2[cw][nl] = a2;
    __syncthreads();
    if (threadIdx.x < 64) {
        s1p[((size_t)b * 5 + cb) * N_DIM + n] = r1[0][nl] + r1[1][nl] + r1[2][nl] + r1[3][nl];
        s2p[((size_t)b * 5 + cb) * N_DIM + n] = r2[0][nl] + r2[1][nl] + r2[2][nl] + r2[3][nl];
    }
}

__global__ __launch_bounds__(1024) void k_fold(const float* __restrict__ s1p,
                                               const float* __restrict__ s2p,
                                               float* __restrict__ s2,
                                               float* __restrict__ Ekf,
                                               float* __restrict__ Gkf,
                                               float* __restrict__ s1max) {
    const int b = blockIdx.x, tid = threadIdx.x;
    __shared__ float md[1024];
    float mx = -3.4e38f;
    for (int n = tid; n < N_DIM; n += 1024) {
        float v1 = 0.f, v2 = 0.f;
        #pragma unroll
        for (int cb = 0; cb < 5; ++cb) {
            v1 += s1p[((size_t)b * 5 + cb) * N_DIM + n];
            v2 += s2p[((size_t)b * 5 + cb) * N_DIM + n];
        }
        s2[b * N_DIM + n] = v2;
        Ekf[b * N_DIM + n] = __expf(v1);
        Gkf[b * N_DIM + n] = __expf(NEG * v1);
        mx = fmaxf(mx, v1);
    }
    md[tid] = mx;
    __syncthreads();
    for (int s = 512; s > 0; s >>= 1) {
        if (tid < s) md[tid] = fmaxf(md[tid], md[tid + s]);
        __syncthreads();
    }
    if (tid == 0) s1max[b] = md[0];
}

__global__ __launch_bounds__(256) void k_z(const float* __restrict__ s2,
                                           const float* __restrict__ s1max,
                                           const float* __restrict__ Ekf,
                                           const float* __restrict__ Gkf,
                                           float* __restrict__ Fz,
                                           float* __restrict__ Hz) {
    __shared__ __align__(16) float Els[4096], Gls[4096];
    const int b = blockIdx.y, tid = threadIdx.x;
    const int w = tid >> 6, l = tid & 63;
    const float* Eb = Ekf + b * N_DIM;
    const float* Gb = Gkf + b * N_DIM;
    #pragma unroll
    for (int i = 0; i < 4; ++i) {
        int chn = i * 256 + tid;
        *(f32x4*)&Els[chn * 4] = *(const f32x4*)&Eb[chn * 4];
        *(f32x4*)&Gls[chn * 4] = *(const f32x4*)&Gb[chn * 4];
    }
    __syncthreads();
    float smax = s1max[b];
    #pragma unroll
    for (int rr = 0; rr < 4; ++rr) {
        int row = b * N_DIM + blockIdx.x * 16 + w * 4 + rr;
        float s2n = s2[row];
        float mn = lrelu(s2n + smax);
        float F = __expf(s2n - mn), H = __expf(NEG * s2n - mn);
        float sum = 0.f;
        #pragma unroll 4
        for (int i = 0; i < 16; ++i) {
            int k = i * 256 + l * 4;
            f32x4 e = *(const f32x4*)&Els[k];
            f32x4 gg = *(const f32x4*)&Gls[k];
            #pragma unroll
            for (int j = 0; j < 4; ++j) sum += fmaxf(e[j] * F, gg[j] * H);
        }
        #pragma unroll
        for (int off = 32; off > 0; off >>= 1) sum += __shfl_down(sum, off);
        if (l == 0) {
            float rz = 1.f / sum;
            Fz[row] = F * rz;
            Hz[row] = H * rz;
        }
    }
}

__global__ __launch_bounds__(128) void k_gemm(const short* __restrict__ xb,
                                              const float* __restrict__ x,
                                              const float* __restrict__ Ekf,
                                              const float* __restrict__ Gkf,
                                              const float* __restrict__ Fz,
                                              const float* __restrict__ Hz,
                                              float* __restrict__ out) {
    __shared__ __align__(16) short Asm[2][2][4096];
    __shared__ __align__(16) float EGs[2][2][256];

    const int b = blockIdx.z, c0 = blockIdx.y * 64, n0 = blockIdx.x * 64;
    const int tid = threadIdx.x;
    const int h = tid >> 6, l = tid & 63, lr = l & 15, g = l >> 4;
    const short* xbp = xb + (size_t)b * C_DIM * N_DIM + h * 2048;
    const float* Eb = Ekf + b * N_DIM + h * 2048;
    const float* Gb = Gkf + b * N_DIM + h * 2048;

    int ncol[4]; float fz[4], hz[4];
    #pragma unroll
    for (int t = 0; t < 4; ++t) {
        int n = n0 + t * 16 + lr;
        ncol[t] = n;
        fz[t] = Fz[b * N_DIM + n];
        hz[t] = Hz[b * N_DIM + n];
    }

    f32x4 acc[4][4];
    #pragma unroll
    for (int i = 0; i < 4; ++i)
        #pragma unroll
        for (int t = 0; t < 4; ++t) acc[i][t] = (f32x4){0.f, 0.f, 0.f, 0.f};

    auto stageA = [&](int buf, int it) {
        #pragma unroll
        for (int i = 0; i < 8; ++i) {
            int row = i * 8 + (l >> 3);
            int c8 = (l & 7) ^ (row & 7);
            gload_lds16(xbp + (size_t)(c0 + row) * N_DIM + it * 64 + c8 * 8,
                        &Asm[h][buf][i * 512]);
        }
    };
    auto stageEG = [&](int buf, int it) {
        int lm = l & 31;
        const float* p = (lm < 16) ? (Eb + it * 64 + lm * 4)
                                   : (Gb + it * 64 + (lm - 16) * 4);
        gload_lds16(p, &EGs[h][buf][0]);
    };

    stageA(0, 0); stageEG(0, 0);
    for (int it = 0; it < 32; ++it) {
        const int buf = it & 1;
        if (it < 31) {
            stageA(buf ^ 1, it + 1);
            stageEG(buf ^ 1, it + 1);
            asm volatile("s_waitcnt vmcnt(9)" ::: "memory");
        } else {
            asm volatile("s_waitcnt vmcnt(0)" ::: "memory");
        }
        __builtin_amdgcn_sched_barrier(0);
        #pragma unroll
        for (int s = 0; s < 2; ++s) {
            const int kk = s * 32 + g * 8;
            f32x4 e0 = *(const f32x4*)&EGs[h][buf][kk];
            f32x4 e1 = *(const f32x4*)&EGs[h][buf][kk + 4];
            f32x4 g0 = *(const f32x4*)&EGs[h][buf][64 + kk];
            f32x4 g1 = *(const f32x4*)&EGs[h][buf][64 + kk + 4];
            bf16x8 afr[4];
            #pragma unroll
            for (int i = 0; i < 4; ++i) {
                int row = 16 * i + lr;
                int idx = row * 64 + (((4 * s + g) ^ (row & 7)) * 8);
                afr[i] = *(const bf16x8*)&Asm[h][buf][idx];
            }
            bf16x8 bfr[4];
            #pragma unroll
            for (int t = 0; t < 4; ++t) {
                bfv8 qv;
                #pragma unroll
                for (int j = 0; j < 4; ++j) {
                    qv[j]     = (__bf16)fmaxf(e0[j] * fz[t], g0[j] * hz[t]);
                    qv[j + 4] = (__bf16)fmaxf(e1[j] * fz[t], g1[j] * hz[t]);
                }
                bfr[t] = __builtin_bit_cast(bf16x8, qv);
            }
            #pragma unroll
            for (int i = 0; i < 4; ++i)
                #pragma unroll
                for (int t = 0; t < 4; ++t)
                    acc[i][t] = __builtin_amdgcn_mfma_f32_16x16x32_bf16(
                        afr[i], bfr[t], acc[i][t], 0, 0, 0);
        }
    }

    __syncthreads();
    float* red = (float*)&Asm[0][0][0];
    if (h == 1) {
        #pragma unroll
        for (int i = 0; i < 4; ++i)
            #pragma unroll
            for (int t = 0; t < 4; ++t)
                #pragma unroll
                for (int r = 0; r < 4; ++r)
                    red[((i * 4 + t) * 4 + r) * 64 + l] = acc[i][t][r];
    }
    __syncthreads();
    if (h == 0) {
        #pragma unroll
        for (int i = 0; i < 4; ++i)
            #pragma unroll
            for (int t = 0; t < 4; ++t)
                #pragma unroll
                for (int r = 0; r < 4; ++r) {
                    float v = acc[i][t][r] + red[((i * 4 + t) * 4 + r) * 64 + l];
                    int c = c0 + 16 * i + g * 4 + r;
                    size_t idx = ((size_t)(b * C_DIM + c)) * N_DIM + ncol[t];
                    out[idx] = v + x[idx];
                }
    }
}

// ============================================================
// launch
// ============================================================

extern "C" void kernel_launch(void* const* d_in, const int* in_sizes, int n_in,
                              void* d_out, int out_size, void* d_ws, size_t ws_size,
                              hipStream_t stream) {
    const float* x = (const float*)d_in[0];
    const float* W = (const float*)d_in[1];
    float* out = (float*)d_out;
    float* ws = (float*)d_ws;

    // ---- new-path ws layout (float offsets) ----
    const size_t o_s1 = 0, o_s2 = 8192, o_S = 16384, o_idx = 24576,
                 o_Eg = 32768, o_Gg = 40960, o_Jn = 49152, o_fz = 57344,
                 o_hz = 65536, o_pc = 73728, o_tot = 139264, o_xT = 221184,
                 o_Tl = 1531904, o_end = 4153344;
    const size_t need_new = o_end * 4;

    // ---- mid-path (round-3) ws layout ----
    const size_t m_s1p = 0, m_s2p = 40960, m_s2 = 81920, m_Ek = 90112,
                 m_Gk = 98304, m_Fz = 106496, m_Hz = 114688, m_mx = 122880,
                 m_xb = 122888;
    const size_t need_mid = m_xb * 4 + (size_t)2 * C_DIM * N_DIM * 2;

    if (ws_size >= need_new) {
        float* s1 = ws + o_s1;
        float* s2 = ws + o_s2;
        float* Sg = ws + o_S;
        int*   idxg = (int*)(ws + o_idx);
        float* Eg = ws + o_Eg;
        float* Gg = ws + o_Gg;
        int*   JnA = (int*)(ws + o_Jn);
        float* fzA = ws + o_fz;
        float* hzA = ws + o_hz;
        int*   pcnt = (int*)(ws + o_pc);
        float* tot = ws + o_tot;
        short* xT = (short*)(ws + o_xT);
        unsigned int* Tloc = (unsigned int*)(ws + o_Tl);

        k_pre   <<<dim3(64, 2), 256, 0, stream>>>(x, W, s1, s2, xT);
        k_rank  <<<dim3(8, 16, 2), 256, 0, stream>>>(s1, pcnt);
        k_sct   <<<2, 1024, 0, stream>>>(s1, s2, pcnt, Sg, idxg, Eg, Gg, JnA, fzA, hzA);
        k_prefix<<<dim3(16, 5, 2), 256, 0, stream>>>(xT, idxg, Eg, Gg, Tloc, tot);
        k_out   <<<dim3(64, 5, 2), 256, 0, stream>>>(x, Tloc, tot, JnA, fzA, hzA, out);
    } else {
        float* s1p = ws + m_s1p;
        float* s2p = ws + m_s2p;
        float* s2  = ws + m_s2;
        float* Ekf = ws + m_Ek;
        float* Gkf = ws + m_Gk;
        float* Fz  = ws + m_Fz;
        float* Hz  = ws + m_Hz;
        float* s1max = ws + m_mx;
        short* xb = (short*)(ws + m_xb);
        k_s12 <<<dim3(64, 5, 2), 256, 0, stream>>>(x, W, s1p, s2p, xb);
        k_fold<<<2, 1024, 0, stream>>>(s1p, s2p, s2, Ekf, Gkf, s1max);
        k_z   <<<dim3(256, 2), 256, 0, stream>>>(s2, s1max, Ekf, Gkf, Fz, Hz);
        k_gemm<<<dim3(64, 5, 2), 128, 0, stream>>>(xb, x, Ekf, Gkf, Fz, Hz, out);
    }
}